// Round 4
// baseline (258.311 us; speedup 1.0000x reference)
//
#include <hip/hip_runtime.h>
#include <stdint.h>

typedef unsigned short ushort_t;
typedef __attribute__((ext_vector_type(4))) unsigned short ushort4_t;
typedef __attribute__((ext_vector_type(8))) short short8;
typedef __attribute__((ext_vector_type(4))) float float4_t;

#define AS1 __attribute__((address_space(1)))
#define AS3 __attribute__((address_space(3)))

__device__ inline ushort_t f2bf(float f) {
    unsigned x = __builtin_bit_cast(unsigned, f);
    unsigned r = x + 0x7fffu + ((x >> 16) & 1u);
    return (ushort_t)(r >> 16);
}
__device__ inline ushort_t f2bf_trunc(float f) {
    return (ushort_t)(__builtin_bit_cast(unsigned, f) >> 16);
}

// ---------- fused prep: transpose W_qkv + convert x ----------
// blocks [0,768): wqkv 1024x3072 -> T bf16; [768,2816): x fp32 -> bf16
__global__ __launch_bounds__(256) void prep_fused(
    const float* __restrict__ wqkv, const float* __restrict__ x,
    ushort_t* __restrict__ wqkvT, ushort_t* __restrict__ xbf) {
    __shared__ __align__(16) ushort_t tile[64][65];
    int bid = blockIdx.x, t = threadIdx.x;
    if (bid < 768) {
        int bx = bid % 48, by = bid / 48;
        int c0 = bx * 64, r0 = by * 64;
        for (int i = 0; i < 16; i++) {
            int idx = t + i * 256;
            int lr = idx >> 6, lc = idx & 63;
            tile[lr][lc] = f2bf(wqkv[(size_t)(r0 + lr) * 3072 + c0 + lc]);
        }
        __syncthreads();
        for (int i = 0; i < 16; i++) {
            int idx = t + i * 256;
            int lr = idx >> 6, lc = idx & 63;
            wqkvT[(size_t)(c0 + lr) * 1024 + r0 + lc] = tile[lc][lr];
        }
    } else {
        size_t i = ((size_t)(bid - 768) * 256 + t) * 8;
        float4_t a = *(const float4_t*)(x + i);
        float4_t b = *(const float4_t*)(x + i + 4);
        ushort_t u[8];
        u[0] = f2bf(a.x); u[1] = f2bf(a.y); u[2] = f2bf(a.z); u[3] = f2bf(a.w);
        u[4] = f2bf(b.x); u[5] = f2bf(b.y); u[6] = f2bf(b.z); u[7] = f2bf(b.w);
        *(ushort4_t*)(xbf + i) = *(ushort4_t*)&u[0];
        *(ushort4_t*)(xbf + i + 4) = *(ushort4_t*)&u[4];
    }
}

// ---------- transpose+convert: in fp32 [R][C] -> out bf16 [C][R] ----------
__global__ __launch_bounds__(256) void transpose_f32_bf16(const float* __restrict__ in,
                                                          ushort_t* __restrict__ out,
                                                          int R, int C) {
    __shared__ __align__(16) ushort_t tile[64][65];
    int c0 = blockIdx.x * 64, r0 = blockIdx.y * 64;
    int t = threadIdx.x;
    for (int i = 0; i < 16; i++) {
        int idx = t + i * 256;
        int lr = idx >> 6, lc = idx & 63;
        tile[lr][lc] = f2bf(in[(size_t)(r0 + lr) * C + c0 + lc]);
    }
    __syncthreads();
    for (int i = 0; i < 16; i++) {
        int idx = t + i * 256;
        int lr = idx >> 6, lc = idx & 63;
        out[(size_t)(c0 + lr) * R + r0 + lc] = tile[lc][lr];
    }
}

// ---------- GEMM1: q/k/v = xbf @ wqkvT^T, scatter to [b,h,n,d] ----------
__global__ __launch_bounds__(256) void gemm_qkv(
    const ushort_t* __restrict__ A, const ushort_t* __restrict__ Bt,
    ushort_t* __restrict__ outQ, ushort_t* __restrict__ outK, ushort_t* __restrict__ outV) {
    const int K = 1024;
    __shared__ __align__(16) ushort_t As[128 * 64];
    __shared__ __align__(16) ushort_t Bs[128 * 64];
    int t = threadIdx.x;
    int w = t >> 6, lane = t & 63;
    int quad = lane >> 4, l15 = lane & 15;
    int wM = w >> 1, wN = w & 1;
    int tM = blockIdx.y * 128, tN = blockIdx.x * 128;

    float4_t acc[4][4];
    for (int i = 0; i < 4; i++)
        for (int j = 0; j < 4; j++) acc[i][j] = (float4_t){0.f, 0.f, 0.f, 0.f};

    int lrow = lane >> 3;
    int lcol8 = (lane & 7) * 8;

    const ushort_t* Abase = A + (size_t)(tM + w * 32) * K;
    const ushort_t* Bbase = Bt + (size_t)(tN + w * 32) * K;

    for (int k0 = 0; k0 < K; k0 += 64) {
        __syncthreads();
        for (int i = 0; i < 4; i++) {
            const ushort_t* ga = Abase + (size_t)(i * 8 + lrow) * K + k0 + lcol8;
            __builtin_amdgcn_global_load_lds((AS1 void*)ga, (AS3 void*)&As[(w * 32 + i * 8) * 64], 16, 0, 0);
            const ushort_t* gb = Bbase + (size_t)(i * 8 + lrow) * K + k0 + lcol8;
            __builtin_amdgcn_global_load_lds((AS1 void*)gb, (AS3 void*)&Bs[(w * 32 + i * 8) * 64], 16, 0, 0);
        }
        __syncthreads();
        for (int kt = 0; kt < 2; kt++) {
            short8 af[4], bf[4];
            for (int m = 0; m < 4; m++)
                af[m] = *(const short8*)&As[(wM * 64 + m * 16 + l15) * 64 + kt * 32 + quad * 8];
            for (int n = 0; n < 4; n++)
                bf[n] = *(const short8*)&Bs[(wN * 64 + n * 16 + l15) * 64 + kt * 32 + quad * 8];
            for (int m = 0; m < 4; m++)
                for (int n = 0; n < 4; n++)
                    acc[m][n] = __builtin_amdgcn_mfma_f32_16x16x32_bf16(af[m], bf[n], acc[m][n], 0, 0, 0);
        }
    }

    for (int m = 0; m < 4; m++) {
        int gm = tM + wM * 64 + m * 16 + quad * 4;
        for (int n = 0; n < 4; n++) {
            int gn = tN + wN * 64 + n * 16 + l15;
            int three = gn >> 10;
            int h = (gn >> 6) & 15;
            int dd = gn & 63;
            ushort_t* dst = (three == 0) ? outQ : (three == 1) ? outK : outV;
            for (int r = 0; r < 4; r++) {
                int row = gm + r;
                int b = row >> 11;
                int ns = row & 2047;
                dst[(((size_t)(b * 16 + h) * 2048 + ns) << 6) + dd] = f2bf(acc[m][n][r]);
            }
        }
    }
}

// ---------- flash attention r9: split-K over key tiles ----------
// Evidence r7/r8: completion = longest block chain (32 iters) x ~1.77us, invariant to
// total work. Fix: fixed-shift softmax (constant -8 bias, no running max) makes
// partials over disjoint key ranges combine LINEARLY (O = sum, ls = sum). Split
// g>=8 tiles into two key-range blocks (max chain 32 -> 16); g<=7 unsplit write
// bf16 directly. Split blocks atomicAdd fp32 partials into zeroed Oacc/lsacc;
// combine_norm normalizes rows n>=1024. Item tables make each CU triple
// {x, x+8, x+16} sum to 34 iterations. LDS 56->48KB (padb -> direct pad loads)
// so 3 blocks/CU co-reside and the three chains run concurrently.
__global__ __launch_bounds__(512, 6) void attn_kernel(
    const ushort_t* __restrict__ q, const ushort_t* __restrict__ k,
    const ushort_t* __restrict__ v, const int* __restrict__ pad,
    const int* __restrict__ csp, ushort_t* __restrict__ out,
    float* __restrict__ Oacc, float* __restrict__ lsacc) {
    __shared__ __align__(16) ushort_t Ks[2][64 * 64];    // [key][dd], XOR-swizzled
    __shared__ __align__(16) ushort_t VsT[2][64 * 64];   // [dd][key], XOR-swizzled
    __shared__ __align__(16) ushort_t Ps[8][16 * 64];    // per-wave P tile

    // item tables: x -> (g, it0, it1); triples {x, x+8, x+16} each sum 34 iters
    const int g_tab[24]  = {0,1,2,3,8,8,4,9, 15,13,12,10,10,11,9,5, 15,7,14,14,6,12,13,11};
    const int t0_tab[24] = {0,0,0,0,0,9,0,10, 0,0,0,0,11,0,0,0,    16,0,0,15,0,13,14,12};
    const int t1_tab[24] = {2,4,6,8,9,18,10,20, 16,14,13,11,22,12,10,12, 32,16,15,30,14,26,28,24};

    int cs = csp[0];
    int t = threadIdx.x, w = t >> 6, lane = t & 63;
    int quad = lane >> 4, l15 = lane & 15;
    int bh = blockIdx.y;
    int b = bh >> 4, h = bh & 15;
    int xi = blockIdx.x;
    int g = g_tab[xi];
    int it0 = t0_tab[xi], it1 = t1_tab[xi];
    bool split = (g >= 8);
    int q0 = g * 128;
    int rowmin = q0 + w * 16;
    const float c1 = 0.18033688f;    // 0.125 * log2(e)
    const float c2 = -11.541560f;    // -8 * log2(e)

    int csT = (cs + 63) >> 6;
    bool lastitem = (g < 8) || (it0 > 0);
    if (lastitem && csT > it1) it1 = csT;

    const ushort_t* qb = q + ((size_t)bh * 2048 + rowmin + l15) * 64;
    short8 qf0 = *(const short8*)(qb + quad * 8);
    short8 qf1 = *(const short8*)(qb + 32 + quad * 8);

    float4_t O[4];
    for (int i = 0; i < 4; i++) O[i] = (float4_t){0.f, 0.f, 0.f, 0.f};
    float ls[4] = {0.f, 0.f, 0.f, 0.f};

    const ushort_t* kbase = k + (size_t)bh * 2048 * 64;
    const ushort_t* vbase = v + (size_t)bh * 2048 * 64;
    const int* padp = pad + b * 2048;

    int lrow = lane >> 3, lblk = lane & 7;
    int prow = rowmin + quad * 4;
    int sw = l15 & 7;

    short8 vr;   // V register-prefetch (one 8-col strip per wave)
    auto stageK = [&](int it, int buf) {
        int k0 = it * 64;
        const ushort_t* gk = kbase + (size_t)(k0 + w * 8 + lrow) * 64 + ((lblk ^ lrow) * 8);
        __builtin_amdgcn_global_load_lds((AS1 void*)gk, (AS3 void*)&Ks[buf][w * 8 * 64], 16, 0, 0);
    };
    auto loadV = [&](int it) {
        vr = *(const short8*)(vbase + (size_t)(it * 64 + lane) * 64 + w * 8);
    };

    stageK(it0, it0 & 1);
    loadV(it0);

    for (int it = it0; it < it1; it++) {
        int cur = it & 1, nxt = cur ^ 1;
        for (int j = 0; j < 8; j++) {
            int sl = ((lrow ^ j) * 8) + lblk;
            VsT[cur][(w * 8 + j) * 64 + sl] = (ushort_t)vr[j];
        }
        __syncthreads();  // drains this tile's K glds; VsT[cur] visible
        if (it + 1 < it1) {
            stageK(it + 1, nxt);
            loadV(it + 1);
        }

        int k0 = it * 64;
        // tile fully causal-masked for this wave? (keys all > rowmax and >= cs)
        bool act = (k0 <= rowmin + 15) || (k0 < cs);
        if (act) {
            // pad values for this tile (coalesced, L2-hot); issued early to hide latency
            int pvv[4];
            for (int ks = 0; ks < 4; ks++) pvv[ks] = padp[k0 + ks * 16 + l15];

            short8 kf0[4], kf1[4];
            for (int ks = 0; ks < 4; ks++) {
                const ushort_t* krow = &Ks[cur][(ks * 16 + l15) * 64];
                kf0[ks] = *(const short8*)(krow + (quad ^ sw) * 8);
                kf1[ks] = *(const short8*)(krow + ((4 + quad) ^ sw) * 8);
            }

            float4_t s[4];
            for (int ks = 0; ks < 4; ks++) {
                float4_t a = (float4_t){0.f, 0.f, 0.f, 0.f};
                a = __builtin_amdgcn_mfma_f32_16x16x32_bf16(qf0, kf0[ks], a, 0, 0, 0);
                a = __builtin_amdgcn_mfma_f32_16x16x32_bf16(qf1, kf1[ks], a, 0, 0, 0);
                s[ks] = a;
            }
            bool needC = (k0 + 63 > rowmin) && (k0 + 63 >= cs);
            for (int ks = 0; ks < 4; ks++) {
                int key = k0 + ks * 16 + l15;
                float add = pvv[ks] ? -1e38f : c2;
                for (int r = 0; r < 4; r++) {
                    float arg = s[ks][r] * c1 + add;
                    if (needC && (key > prow + r) && (key >= cs)) arg = -1e38f;
                    float p = __builtin_amdgcn_exp2f(arg);
                    ls[r] += p;
                    int row = quad * 4 + r;
                    Ps[w][row * 64 + (((ks * 2 + (l15 >> 3)) ^ (row & 7)) * 8) + (l15 & 7)] = f2bf_trunc(p);
                }
            }

            short8 vf0[4], vf1[4];
            for (int n = 0; n < 4; n++) {
                const ushort_t* vrow = &VsT[cur][(n * 16 + l15) * 64];
                vf0[n] = *(const short8*)(vrow + (quad ^ sw) * 8);
                vf1[n] = *(const short8*)(vrow + ((4 + quad) ^ sw) * 8);
            }
            const ushort_t* prl = &Ps[w][l15 * 64];
            short8 pf0 = *(const short8*)(prl + (quad ^ sw) * 8);
            short8 pf1 = *(const short8*)(prl + ((4 + quad) ^ sw) * 8);
            for (int n = 0; n < 4; n++) {
                O[n] = __builtin_amdgcn_mfma_f32_16x16x32_bf16(pf0, vf0[n], O[n], 0, 0, 0);
                O[n] = __builtin_amdgcn_mfma_f32_16x16x32_bf16(pf1, vf1[n], O[n], 0, 0, 0);
            }
        }
    }

    if (!split) {
        for (int r = 0; r < 4; r++) {
            float l = ls[r];
            l += __shfl_xor(l, 1, 64); l += __shfl_xor(l, 2, 64);
            l += __shfl_xor(l, 4, 64); l += __shfl_xor(l, 8, 64);
            float inv = l > 0.f ? 1.f / l : 0.f;
            int row = rowmin + quad * 4 + r;
            size_t ob = ((size_t)b * 2048 + row) * 1024 + h * 64;
            for (int n = 0; n < 4; n++)
                out[ob + n * 16 + l15] = f2bf(O[n][r] * inv);
        }
    } else {
        for (int r = 0; r < 4; r++) {
            float l = ls[r];
            l += __shfl_xor(l, 1, 64); l += __shfl_xor(l, 2, 64);
            l += __shfl_xor(l, 4, 64); l += __shfl_xor(l, 8, 64);
            int row = rowmin + quad * 4 + r;   // in [1024, 2048)
            int rn = row - 1024;
            if (l15 == 0) atomicAdd(&lsacc[bh * 1024 + rn], l);
            float* orow = Oacc + ((size_t)(b * 1024 + rn)) * 1024 + h * 64;
            for (int n = 0; n < 4; n++)
                atomicAdd(&orow[n * 16 + l15], O[n][r]);
        }
    }
}

// ---------- combine split-K partials: aows[b][1024+rn][c] = Oacc/lsacc ----------
__global__ __launch_bounds__(256) void combine_norm(
    const float* __restrict__ Oacc, const float* __restrict__ lsacc,
    ushort_t* __restrict__ aows) {
    int rid = blockIdx.x;            // [0,2048): b = rid>>10, rn = rid&1023
    int b = rid >> 10, rn = rid & 1023;
    int c0 = threadIdx.x * 4;
    const float* orow = Oacc + (size_t)rid * 1024;
    float4_t o = *(const float4_t*)(orow + c0);
    int h = c0 >> 6;
    float l = lsacc[(b * 16 + h) * 1024 + rn];
    float inv = l > 0.f ? 1.f / l : 0.f;
    ushort_t u[4];
    u[0] = f2bf(o.x * inv); u[1] = f2bf(o.y * inv);
    u[2] = f2bf(o.z * inv); u[3] = f2bf(o.w * inv);
    *(ushort4_t*)(aows + ((size_t)(b * 2048 + 1024 + rn)) * 1024 + c0) = *(ushort4_t*)u;
}

// ---------- GEMM2: out = ao @ wprojT^T + bias (bf16 A via glds, fp32 out) ----------
__global__ __launch_bounds__(256) void gemm_out_k(
    const ushort_t* __restrict__ A, const ushort_t* __restrict__ Bt,
    const float* __restrict__ bias, float* __restrict__ outC) {
    const int K = 1024, N = 1024;
    __shared__ __align__(16) ushort_t As[128 * 64];
    __shared__ __align__(16) ushort_t Bs[128 * 64];
    int t = threadIdx.x;
    int w = t >> 6, lane = t & 63;
    int quad = lane >> 4, l15 = lane & 15;
    int wM = w >> 1, wN = w & 1;
    int tM = blockIdx.y * 128, tN = blockIdx.x * 128;

    float4_t acc[4][4];
    for (int i = 0; i < 4; i++)
        for (int j = 0; j < 4; j++) acc[i][j] = (float4_t){0.f, 0.f, 0.f, 0.f};

    int lrow = lane >> 3;
    int lcol8 = (lane & 7) * 8;

    const ushort_t* Abase = A + (size_t)(tM + w * 32) * K;
    const ushort_t* Bbase = Bt + (size_t)(tN + w * 32) * K;

    for (int k0 = 0; k0 < K; k0 += 64) {
        __syncthreads();
        for (int i = 0; i < 4; i++) {
            const ushort_t* ga = Abase + (size_t)(i * 8 + lrow) * K + k0 + lcol8;
            __builtin_amdgcn_global_load_lds((AS1 void*)ga, (AS3 void*)&As[(w * 32 + i * 8) * 64], 16, 0, 0);
            const ushort_t* gb = Bbase + (size_t)(i * 8 + lrow) * K + k0 + lcol8;
            __builtin_amdgcn_global_load_lds((AS1 void*)gb, (AS3 void*)&Bs[(w * 32 + i * 8) * 64], 16, 0, 0);
        }
        __syncthreads();
        for (int kt = 0; kt < 2; kt++) {
            short8 af[4], bf[4];
            for (int m = 0; m < 4; m++)
                af[m] = *(const short8*)&As[(wM * 64 + m * 16 + l15) * 64 + kt * 32 + quad * 8];
            for (int n = 0; n < 4; n++)
                bf[n] = *(const short8*)&Bs[(wN * 64 + n * 16 + l15) * 64 + kt * 32 + quad * 8];
            for (int m = 0; m < 4; m++)
                for (int n = 0; n < 4; n++)
                    acc[m][n] = __builtin_amdgcn_mfma_f32_16x16x32_bf16(af[m], bf[n], acc[m][n], 0, 0, 0);
        }
    }

    for (int m = 0; m < 4; m++) {
        int gm = tM + wM * 64 + m * 16 + quad * 4;
        for (int n = 0; n < 4; n++) {
            int gn = tN + wN * 64 + n * 16 + l15;
            float bv = bias[gn];
            for (int r = 0; r < 4; r++)
                outC[(size_t)(gm + r) * N + gn] = acc[m][n][r] + bv;
        }
    }
}

extern "C" void kernel_launch(void* const* d_in, const int* in_sizes, int n_in,
                              void* d_out, int out_size, void* d_ws, size_t ws_size,
                              hipStream_t stream) {
    const float* x = (const float*)d_in[0];
    const int* pad = (const int*)d_in[1];
    const int* cs = (const int*)d_in[2];
    const float* wqkv = (const float*)d_in[3];
    const float* wproj = (const float*)d_in[4];
    const float* bproj = (const float*)d_in[5];
    float* out = (float*)d_out;

    // ws (peak 32 MB, lifetimes audited):
    //   q[0,8M) k[8,16M) v[16,24M)        gemm1 -> attn
    //   wqkvT[24,30M)                     prep -> gemm1 (dies)
    //   ao bf16 [24,32M)                  attn/combine -> gemm2 (over dead wqkvT)
    //   wprojT[0,2M)                      transposed AFTER attn (over dead q)
    // d_out (16MB): xbf bf16 [0,8M) prep -> gemm1 (dies);
    //   then Oacc fp32 [0,8M) + lsacc fp32 [8M,8.125M) (memset after gemm1,
    //   atomically accumulated by attn split blocks, read by combine_norm);
    //   final fp32 out written by gemm2 (after combine_norm has read Oacc).
    ushort_t* ws = (ushort_t*)d_ws;
    ushort_t* qws = ws;
    ushort_t* kws = ws + (size_t)4194304;
    ushort_t* vws = ws + (size_t)8388608;
    ushort_t* wqkvT = ws + (size_t)12582912;
    ushort_t* aows = ws + (size_t)12582912;
    ushort_t* wprojT = ws;
    ushort_t* xbf = (ushort_t*)d_out;
    float* Oacc = (float*)d_out;
    float* lsacc = (float*)d_out + 2097152;

    prep_fused<<<2816, 256, 0, stream>>>(wqkv, x, wqkvT, xbf);
    gemm_qkv<<<dim3(24, 32), 256, 0, stream>>>(xbf, wqkvT, qws, kws, vws);
    hipMemsetAsync(d_out, 0, (size_t)(2097152 + 32768) * 4, stream);
    attn_kernel<<<dim3(24, 32), 512, 0, stream>>>(qws, kws, vws, pad, cs, aows, Oacc, lsacc);
    transpose_f32_bf16<<<dim3(16, 16), 256, 0, stream>>>(wproj, wprojT, 1024, 1024);
    combine_norm<<<2048, 256, 0, stream>>>(Oacc, lsacc, aows);
    gemm_out_k<<<dim3(8, 32), 256, 0, stream>>>(aows, wprojT, bproj, out);
}

// Round 5
// 256.780 us; speedup vs baseline: 1.0060x; 1.0060x over previous
//
#include <hip/hip_runtime.h>
#include <stdint.h>

typedef unsigned short ushort_t;
typedef __attribute__((ext_vector_type(4))) unsigned short ushort4_t;
typedef __attribute__((ext_vector_type(8))) short short8;
typedef __attribute__((ext_vector_type(4))) float float4_t;

#define AS1 __attribute__((address_space(1)))
#define AS3 __attribute__((address_space(3)))

__device__ inline ushort_t f2bf(float f) {
    unsigned x = __builtin_bit_cast(unsigned, f);
    unsigned r = x + 0x7fffu + ((x >> 16) & 1u);
    return (ushort_t)(r >> 16);
}
__device__ inline ushort_t f2bf_trunc(float f) {
    return (ushort_t)(__builtin_bit_cast(unsigned, f) >> 16);
}

// ---------- fused prep: transpose W_qkv + convert x ----------
// blocks [0,768): wqkv 1024x3072 -> T bf16; [768,2816): x fp32 -> bf16
__global__ __launch_bounds__(256) void prep_fused(
    const float* __restrict__ wqkv, const float* __restrict__ x,
    ushort_t* __restrict__ wqkvT, ushort_t* __restrict__ xbf) {
    __shared__ __align__(16) ushort_t tile[64][65];
    int bid = blockIdx.x, t = threadIdx.x;
    if (bid < 768) {
        int bx = bid % 48, by = bid / 48;
        int c0 = bx * 64, r0 = by * 64;
        for (int i = 0; i < 16; i++) {
            int idx = t + i * 256;
            int lr = idx >> 6, lc = idx & 63;
            tile[lr][lc] = f2bf(wqkv[(size_t)(r0 + lr) * 3072 + c0 + lc]);
        }
        __syncthreads();
        for (int i = 0; i < 16; i++) {
            int idx = t + i * 256;
            int lr = idx >> 6, lc = idx & 63;
            wqkvT[(size_t)(c0 + lr) * 1024 + r0 + lc] = tile[lc][lr];
        }
    } else {
        size_t i = ((size_t)(bid - 768) * 256 + t) * 8;
        float4_t a = *(const float4_t*)(x + i);
        float4_t b = *(const float4_t*)(x + i + 4);
        ushort_t u[8];
        u[0] = f2bf(a.x); u[1] = f2bf(a.y); u[2] = f2bf(a.z); u[3] = f2bf(a.w);
        u[4] = f2bf(b.x); u[5] = f2bf(b.y); u[6] = f2bf(b.z); u[7] = f2bf(b.w);
        *(ushort4_t*)(xbf + i) = *(ushort4_t*)&u[0];
        *(ushort4_t*)(xbf + i + 4) = *(ushort4_t*)&u[4];
    }
}

// ---------- transpose+convert: in fp32 [R][C] -> out bf16 [C][R] ----------
__global__ __launch_bounds__(256) void transpose_f32_bf16(const float* __restrict__ in,
                                                          ushort_t* __restrict__ out,
                                                          int R, int C) {
    __shared__ __align__(16) ushort_t tile[64][65];
    int c0 = blockIdx.x * 64, r0 = blockIdx.y * 64;
    int t = threadIdx.x;
    for (int i = 0; i < 16; i++) {
        int idx = t + i * 256;
        int lr = idx >> 6, lc = idx & 63;
        tile[lr][lc] = f2bf(in[(size_t)(r0 + lr) * C + c0 + lc]);
    }
    __syncthreads();
    for (int i = 0; i < 16; i++) {
        int idx = t + i * 256;
        int lr = idx >> 6, lc = idx & 63;
        out[(size_t)(c0 + lr) * R + r0 + lc] = tile[lc][lr];
    }
}

// ---------- GEMM1: q/k/v = xbf @ wqkvT^T, scatter to [b,h,n,d] ----------
__global__ __launch_bounds__(256) void gemm_qkv(
    const ushort_t* __restrict__ A, const ushort_t* __restrict__ Bt,
    ushort_t* __restrict__ outQ, ushort_t* __restrict__ outK, ushort_t* __restrict__ outV) {
    const int K = 1024;
    __shared__ __align__(16) ushort_t As[128 * 64];
    __shared__ __align__(16) ushort_t Bs[128 * 64];
    int t = threadIdx.x;
    int w = t >> 6, lane = t & 63;
    int quad = lane >> 4, l15 = lane & 15;
    int wM = w >> 1, wN = w & 1;
    int tM = blockIdx.y * 128, tN = blockIdx.x * 128;

    float4_t acc[4][4];
    for (int i = 0; i < 4; i++)
        for (int j = 0; j < 4; j++) acc[i][j] = (float4_t){0.f, 0.f, 0.f, 0.f};

    int lrow = lane >> 3;
    int lcol8 = (lane & 7) * 8;

    const ushort_t* Abase = A + (size_t)(tM + w * 32) * K;
    const ushort_t* Bbase = Bt + (size_t)(tN + w * 32) * K;

    for (int k0 = 0; k0 < K; k0 += 64) {
        __syncthreads();
        for (int i = 0; i < 4; i++) {
            const ushort_t* ga = Abase + (size_t)(i * 8 + lrow) * K + k0 + lcol8;
            __builtin_amdgcn_global_load_lds((AS1 void*)ga, (AS3 void*)&As[(w * 32 + i * 8) * 64], 16, 0, 0);
            const ushort_t* gb = Bbase + (size_t)(i * 8 + lrow) * K + k0 + lcol8;
            __builtin_amdgcn_global_load_lds((AS1 void*)gb, (AS3 void*)&Bs[(w * 32 + i * 8) * 64], 16, 0, 0);
        }
        __syncthreads();
        for (int kt = 0; kt < 2; kt++) {
            short8 af[4], bf[4];
            for (int m = 0; m < 4; m++)
                af[m] = *(const short8*)&As[(wM * 64 + m * 16 + l15) * 64 + kt * 32 + quad * 8];
            for (int n = 0; n < 4; n++)
                bf[n] = *(const short8*)&Bs[(wN * 64 + n * 16 + l15) * 64 + kt * 32 + quad * 8];
            for (int m = 0; m < 4; m++)
                for (int n = 0; n < 4; n++)
                    acc[m][n] = __builtin_amdgcn_mfma_f32_16x16x32_bf16(af[m], bf[n], acc[m][n], 0, 0, 0);
        }
    }

    for (int m = 0; m < 4; m++) {
        int gm = tM + wM * 64 + m * 16 + quad * 4;
        for (int n = 0; n < 4; n++) {
            int gn = tN + wN * 64 + n * 16 + l15;
            int three = gn >> 10;
            int h = (gn >> 6) & 15;
            int dd = gn & 63;
            ushort_t* dst = (three == 0) ? outQ : (three == 1) ? outK : outV;
            for (int r = 0; r < 4; r++) {
                int row = gm + r;
                int b = row >> 11;
                int ns = row & 2047;
                dst[(((size_t)(b * 16 + h) * 2048 + ns) << 6) + dd] = f2bf(acc[m][n][r]);
            }
        }
    }
}

// ---------- flash attention r10: split-K with private fp32 partials (NO atomics) ----------
// Chain model (r7/r8): completion = longest serial block chain x ~1.77us. Split g>=8
// q-tiles into two contiguous key-range halves -> max chain 16 iters. Fixed-shift
// softmax (constant -8 bias) makes partials combine linearly: O = O_A + O_B,
// l = l_A + l_B. Each half writes its FULL partial to a private region:
//   Oacc[half][bh][row-1024][64] fp32 (2 x 8MB in d_out, over dead xbf; no memset)
//   ls partials (32 floats: 16 h x 2 halves) embedded in first 128B of the aows row
//   that combine_norm itself overwrites (read-then-write same block -> no race).
// Grid (24,32): co-resident triples are {x, (x+8)%24, (x+16)%24} (linear ids differ
// by 256 = 24*10+16, CU = linear%256), i.e. x congruent mod 8. Item tables below
// make every such triple sum to exactly 34 iterations. LDS 48KB -> 3 blocks/CU.
__global__ __launch_bounds__(512, 6) void attn_kernel(
    const ushort_t* __restrict__ q, const ushort_t* __restrict__ k,
    const ushort_t* __restrict__ v, const int* __restrict__ pad,
    const int* __restrict__ csp, ushort_t* __restrict__ out,
    float* __restrict__ Oacc) {
    __shared__ __align__(16) ushort_t Ks[2][64 * 64];    // [key][dd], XOR-swizzled
    __shared__ __align__(16) ushort_t VsT[2][64 * 64];   // [dd][key], XOR-swizzled
    __shared__ __align__(16) ushort_t Ps[8][16 * 64];    // per-wave P tile

    // x -> (g, mode): mode 0=unsplit, 1=half A (keys [0,hp)), 2=half B (keys [hp,nT))
    // iters: U(g)=2g+2; A/B(g)=g+1. Triples {x,x+8,x+16} (mod 24) each sum 34:
    // {2,16,16} {4,16,14} {6,14,14} {8,13,13} {10,12,12} {12,11,11} {9,10,15} {9,10,15}
    const int g_tab[24] = {0,1,2,3,4,5,8,8, 15,7,6,12,11,10,9,9, 15,13,13,12,11,10,14,14};
    const int m_tab[24] = {0,0,0,0,0,0,1,2, 1,0,0,1,1,1,1,2, 2,1,2,2,2,2,1,2};

    int cs = csp[0];
    int t = threadIdx.x, w = t >> 6, lane = t & 63;
    int quad = lane >> 4, l15 = lane & 15;
    int bh = blockIdx.y;
    int b = bh >> 4, h = bh & 15;
    int xi = blockIdx.x;
    int g = g_tab[xi];
    int m = m_tab[xi];
    int q0 = g * 128;
    int rowmin = q0 + w * 16;
    const float c1 = 0.18033688f;    // 0.125 * log2(e)
    const float c2 = -11.541560f;    // -8 * log2(e)

    int csT = (cs + 63) >> 6;
    int nTs = 2 * g + 2;
    if (csT > nTs) nTs = csT;
    int hp = (nTs + 1) >> 1;
    int it0 = (m == 2) ? hp : 0;
    int it1 = (m == 1) ? hp : nTs;

    const ushort_t* qb = q + ((size_t)bh * 2048 + rowmin + l15) * 64;
    short8 qf0 = *(const short8*)(qb + quad * 8);
    short8 qf1 = *(const short8*)(qb + 32 + quad * 8);

    float4_t O[4];
    for (int i = 0; i < 4; i++) O[i] = (float4_t){0.f, 0.f, 0.f, 0.f};
    float ls[4] = {0.f, 0.f, 0.f, 0.f};

    const ushort_t* kbase = k + (size_t)bh * 2048 * 64;
    const ushort_t* vbase = v + (size_t)bh * 2048 * 64;
    const int* padp = pad + b * 2048;

    int lrow = lane >> 3, lblk = lane & 7;
    int prow = rowmin + quad * 4;
    int sw = l15 & 7;

    short8 vr;   // V register-prefetch (one 8-col strip per wave)
    auto stageK = [&](int it, int buf) {
        int k0 = it * 64;
        const ushort_t* gk = kbase + (size_t)(k0 + w * 8 + lrow) * 64 + ((lblk ^ lrow) * 8);
        __builtin_amdgcn_global_load_lds((AS1 void*)gk, (AS3 void*)&Ks[buf][w * 8 * 64], 16, 0, 0);
    };
    auto loadV = [&](int it) {
        vr = *(const short8*)(vbase + (size_t)(it * 64 + lane) * 64 + w * 8);
    };

    stageK(it0, it0 & 1);
    loadV(it0);

    for (int it = it0; it < it1; it++) {
        int cur = it & 1, nxt = cur ^ 1;
        for (int j = 0; j < 8; j++) {
            int sl = ((lrow ^ j) * 8) + lblk;
            VsT[cur][(w * 8 + j) * 64 + sl] = (ushort_t)vr[j];
        }
        __syncthreads();  // drains this tile's K glds; VsT[cur] visible
        if (it + 1 < it1) {
            stageK(it + 1, nxt);
            loadV(it + 1);
        }

        int k0 = it * 64;
        // tile fully causal-masked for this wave? (keys all > rowmax and >= cs)
        bool act = (k0 <= rowmin + 15) || (k0 < cs);
        if (act) {
            // pad values for this tile (coalesced, L2-hot)
            int pvv[4];
            for (int ks = 0; ks < 4; ks++) pvv[ks] = padp[k0 + ks * 16 + l15];

            short8 kf0[4], kf1[4];
            for (int ks = 0; ks < 4; ks++) {
                const ushort_t* krow = &Ks[cur][(ks * 16 + l15) * 64];
                kf0[ks] = *(const short8*)(krow + (quad ^ sw) * 8);
                kf1[ks] = *(const short8*)(krow + ((4 + quad) ^ sw) * 8);
            }

            float4_t s[4];
            for (int ks = 0; ks < 4; ks++) {
                float4_t a = (float4_t){0.f, 0.f, 0.f, 0.f};
                a = __builtin_amdgcn_mfma_f32_16x16x32_bf16(qf0, kf0[ks], a, 0, 0, 0);
                a = __builtin_amdgcn_mfma_f32_16x16x32_bf16(qf1, kf1[ks], a, 0, 0, 0);
                s[ks] = a;
            }
            bool needC = (k0 + 63 > rowmin) && (k0 + 63 >= cs);
            for (int ks = 0; ks < 4; ks++) {
                int key = k0 + ks * 16 + l15;
                float add = pvv[ks] ? -1e38f : c2;
                for (int r = 0; r < 4; r++) {
                    float arg = s[ks][r] * c1 + add;
                    if (needC && (key > prow + r) && (key >= cs)) arg = -1e38f;
                    float p = __builtin_amdgcn_exp2f(arg);
                    ls[r] += p;
                    int row = quad * 4 + r;
                    Ps[w][row * 64 + (((ks * 2 + (l15 >> 3)) ^ (row & 7)) * 8) + (l15 & 7)] = f2bf_trunc(p);
                }
            }

            short8 vf0[4], vf1[4];
            for (int n = 0; n < 4; n++) {
                const ushort_t* vrow = &VsT[cur][(n * 16 + l15) * 64];
                vf0[n] = *(const short8*)(vrow + (quad ^ sw) * 8);
                vf1[n] = *(const short8*)(vrow + ((4 + quad) ^ sw) * 8);
            }
            const ushort_t* prl = &Ps[w][l15 * 64];
            short8 pf0 = *(const short8*)(prl + (quad ^ sw) * 8);
            short8 pf1 = *(const short8*)(prl + ((4 + quad) ^ sw) * 8);
            for (int n = 0; n < 4; n++) {
                O[n] = __builtin_amdgcn_mfma_f32_16x16x32_bf16(pf0, vf0[n], O[n], 0, 0, 0);
                O[n] = __builtin_amdgcn_mfma_f32_16x16x32_bf16(pf1, vf1[n], O[n], 0, 0, 0);
            }
        }
    }

    if (m == 0) {
        for (int r = 0; r < 4; r++) {
            float l = ls[r];
            l += __shfl_xor(l, 1, 64); l += __shfl_xor(l, 2, 64);
            l += __shfl_xor(l, 4, 64); l += __shfl_xor(l, 8, 64);
            float inv = l > 0.f ? 1.f / l : 0.f;
            int row = rowmin + quad * 4 + r;
            size_t ob = ((size_t)b * 2048 + row) * 1024 + h * 64;
            for (int n = 0; n < 4; n++)
                out[ob + n * 16 + l15] = f2bf(O[n][r] * inv);
        }
    } else {
        int hf = m - 1;  // 0 = half A, 1 = half B
        // private partial region: Oacc[hf][bh][row-1024][64] fp32, plain stores
        float* Oh = Oacc + (size_t)hf * 2097152 +
                    ((size_t)bh * 1024 + (rowmin - 1024 + quad * 4)) * 64;
        for (int r = 0; r < 4; r++) {
            float l = ls[r];
            l += __shfl_xor(l, 1, 64); l += __shfl_xor(l, 2, 64);
            l += __shfl_xor(l, 4, 64); l += __shfl_xor(l, 8, 64);
            int row = rowmin + quad * 4 + r;
            float* orow = Oh + (size_t)r * 64;
            for (int n = 0; n < 4; n++)
                orow[n * 16 + l15] = O[n][r];
            // ls partial -> first 128B of the aows row combine_norm will overwrite
            if (l15 == 0)
                *(float*)(out + ((size_t)(b * 2048 + row)) * 1024 + (h * 2 + hf) * 2) = l;
        }
    }
}

// ---------- combine split-K partials: aows row = (OA+OB) / (lsA+lsB), bf16 ----------
__global__ __launch_bounds__(256) void combine_norm(
    const float* __restrict__ Oacc, ushort_t* __restrict__ aows) {
    __shared__ float lsv[32];
    int rid = blockIdx.x;            // [0,2048): b = rid>>10, rn = rid&1023
    int b = rid >> 10, rn = rid & 1023;
    int t = threadIdx.x;
    ushort_t* rowp = aows + ((size_t)(b * 2048 + 1024 + rn)) * 1024;
    if (t < 32) lsv[t] = ((const float*)rowp)[t];
    __syncthreads();
    int c0 = t * 4;
    int h = c0 >> 6;
    int bh = b * 16 + h;
    const float* pa = Oacc + ((size_t)bh * 1024 + rn) * 64 + (c0 & 63);
    float4_t oa = *(const float4_t*)pa;
    float4_t ob = *(const float4_t*)(pa + 2097152);
    float l = lsv[h * 2] + lsv[h * 2 + 1];
    float inv = l > 0.f ? 1.f / l : 0.f;
    ushort_t u[4];
    u[0] = f2bf((oa.x + ob.x) * inv);
    u[1] = f2bf((oa.y + ob.y) * inv);
    u[2] = f2bf((oa.z + ob.z) * inv);
    u[3] = f2bf((oa.w + ob.w) * inv);
    *(ushort4_t*)(rowp + c0) = *(ushort4_t*)u;
}

// ---------- GEMM2: out = ao @ wprojT^T + bias (bf16 A via glds, fp32 out) ----------
__global__ __launch_bounds__(256) void gemm_out_k(
    const ushort_t* __restrict__ A, const ushort_t* __restrict__ Bt,
    const float* __restrict__ bias, float* __restrict__ outC) {
    const int K = 1024, N = 1024;
    __shared__ __align__(16) ushort_t As[128 * 64];
    __shared__ __align__(16) ushort_t Bs[128 * 64];
    int t = threadIdx.x;
    int w = t >> 6, lane = t & 63;
    int quad = lane >> 4, l15 = lane & 15;
    int wM = w >> 1, wN = w & 1;
    int tM = blockIdx.y * 128, tN = blockIdx.x * 128;

    float4_t acc[4][4];
    for (int i = 0; i < 4; i++)
        for (int j = 0; j < 4; j++) acc[i][j] = (float4_t){0.f, 0.f, 0.f, 0.f};

    int lrow = lane >> 3;
    int lcol8 = (lane & 7) * 8;

    const ushort_t* Abase = A + (size_t)(tM + w * 32) * K;
    const ushort_t* Bbase = Bt + (size_t)(tN + w * 32) * K;

    for (int k0 = 0; k0 < K; k0 += 64) {
        __syncthreads();
        for (int i = 0; i < 4; i++) {
            const ushort_t* ga = Abase + (size_t)(i * 8 + lrow) * K + k0 + lcol8;
            __builtin_amdgcn_global_load_lds((AS1 void*)ga, (AS3 void*)&As[(w * 32 + i * 8) * 64], 16, 0, 0);
            const ushort_t* gb = Bbase + (size_t)(i * 8 + lrow) * K + k0 + lcol8;
            __builtin_amdgcn_global_load_lds((AS1 void*)gb, (AS3 void*)&Bs[(w * 32 + i * 8) * 64], 16, 0, 0);
        }
        __syncthreads();
        for (int kt = 0; kt < 2; kt++) {
            short8 af[4], bf[4];
            for (int m = 0; m < 4; m++)
                af[m] = *(const short8*)&As[(wM * 64 + m * 16 + l15) * 64 + kt * 32 + quad * 8];
            for (int n = 0; n < 4; n++)
                bf[n] = *(const short8*)&Bs[(wN * 64 + n * 16 + l15) * 64 + kt * 32 + quad * 8];
            for (int m = 0; m < 4; m++)
                for (int n = 0; n < 4; n++)
                    acc[m][n] = __builtin_amdgcn_mfma_f32_16x16x32_bf16(af[m], bf[n], acc[m][n], 0, 0, 0);
        }
    }

    for (int m = 0; m < 4; m++) {
        int gm = tM + wM * 64 + m * 16 + quad * 4;
        for (int n = 0; n < 4; n++) {
            int gn = tN + wN * 64 + n * 16 + l15;
            float bv = bias[gn];
            for (int r = 0; r < 4; r++)
                outC[(size_t)(gm + r) * N + gn] = acc[m][n][r] + bv;
        }
    }
}

extern "C" void kernel_launch(void* const* d_in, const int* in_sizes, int n_in,
                              void* d_out, int out_size, void* d_ws, size_t ws_size,
                              hipStream_t stream) {
    const float* x = (const float*)d_in[0];
    const int* pad = (const int*)d_in[1];
    const int* cs = (const int*)d_in[2];
    const float* wqkv = (const float*)d_in[3];
    const float* wproj = (const float*)d_in[4];
    const float* bproj = (const float*)d_in[5];
    float* out = (float*)d_out;

    // ws (peak 32 MB, lifetimes audited):
    //   q[0,8M) k[8,16M) v[16,24M)        gemm1 -> attn
    //   wqkvT[24,30M)                     prep -> gemm1 (dies)
    //   ao bf16 [24,32M)                  attn/combine -> gemm2 (over dead wqkvT)
    //     rows n<1024 written by unsplit attn blocks; rows n>=1024: attn split
    //     blocks stash 32 ls floats in the first 128B, combine_norm reads them
    //     then overwrites the row with normalized bf16.
    //   wprojT[0,2M)                      transposed AFTER attn (over dead q)
    // d_out (16MB): xbf bf16 [0,8M) prep -> gemm1 (dies);
    //   then Oacc fp32 [half][bh][1024][64]: half A [0,8M), half B [8,16M)
    //   (plain stores by attn split blocks, read by combine_norm);
    //   final fp32 out written by gemm2 (after combine_norm consumed Oacc).
    ushort_t* ws = (ushort_t*)d_ws;
    ushort_t* qws = ws;
    ushort_t* kws = ws + (size_t)4194304;
    ushort_t* vws = ws + (size_t)8388608;
    ushort_t* wqkvT = ws + (size_t)12582912;
    ushort_t* aows = ws + (size_t)12582912;
    ushort_t* wprojT = ws;
    ushort_t* xbf = (ushort_t*)d_out;
    float* Oacc = (float*)d_out;

    prep_fused<<<2816, 256, 0, stream>>>(wqkv, x, wqkvT, xbf);
    gemm_qkv<<<dim3(24, 32), 256, 0, stream>>>(xbf, wqkvT, qws, kws, vws);
    attn_kernel<<<dim3(24, 32), 512, 0, stream>>>(qws, kws, vws, pad, cs, aows, Oacc);
    transpose_f32_bf16<<<dim3(16, 16), 256, 0, stream>>>(wproj, wprojT, 1024, 1024);
    combine_norm<<<2048, 256, 0, stream>>>(Oacc, aows);
    gemm_out_k<<<dim3(8, 32), 256, 0, stream>>>(aows, wprojT, bproj, out);
}

// Round 7
// 200.087 us; speedup vs baseline: 1.2910x; 1.2833x over previous
//
#include <hip/hip_runtime.h>
#include <stdint.h>

typedef unsigned short ushort_t;
typedef __attribute__((ext_vector_type(4))) unsigned short ushort4_t;
typedef __attribute__((ext_vector_type(8))) short short8;
typedef __attribute__((ext_vector_type(4))) float float4_t;

#define AS1 __attribute__((address_space(1)))
#define AS3 __attribute__((address_space(3)))

__device__ inline ushort_t f2bf(float f) {
    unsigned x = __builtin_bit_cast(unsigned, f);
    unsigned r = x + 0x7fffu + ((x >> 16) & 1u);
    return (ushort_t)(r >> 16);
}
__device__ inline ushort_t f2bf_trunc(float f) {
    return (ushort_t)(__builtin_bit_cast(unsigned, f) >> 16);
}

// ---------- fused prep: transpose W_qkv + convert x + pad-mask scan ----------
// blocks [0,768): wqkv 1024x3072 -> T bf16; [768,2816): x fp32 -> bf16;
// [2816,2818): per-batch prefix scan of padding mask -> cvtab/pref/idxmap/vcp.
__global__ __launch_bounds__(256) void prep_fused(
    const float* __restrict__ wqkv, const float* __restrict__ x,
    const int* __restrict__ pad,
    ushort_t* __restrict__ wqkvT, ushort_t* __restrict__ xbf,
    int* __restrict__ tbl) {
    __shared__ __align__(16) ushort_t tile[64][65];
    __shared__ int wsum[4];
    int bid = blockIdx.x, t = threadIdx.x;
    if (bid < 768) {
        int bx = bid % 48, by = bid / 48;
        int c0 = bx * 64, r0 = by * 64;
        for (int i = 0; i < 16; i++) {
            int idx = t + i * 256;
            int lr = idx >> 6, lc = idx & 63;
            tile[lr][lc] = f2bf(wqkv[(size_t)(r0 + lr) * 3072 + c0 + lc]);
        }
        __syncthreads();
        for (int i = 0; i < 16; i++) {
            int idx = t + i * 256;
            int lr = idx >> 6, lc = idx & 63;
            wqkvT[(size_t)(c0 + lr) * 1024 + r0 + lc] = tile[lc][lr];
        }
    } else if (bid < 2816) {
        size_t i = ((size_t)(bid - 768) * 256 + t) * 8;
        float4_t a = *(const float4_t*)(x + i);
        float4_t b = *(const float4_t*)(x + i + 4);
        ushort_t u[8];
        u[0] = f2bf(a.x); u[1] = f2bf(a.y); u[2] = f2bf(a.z); u[3] = f2bf(a.w);
        u[4] = f2bf(b.x); u[5] = f2bf(b.y); u[6] = f2bf(b.z); u[7] = f2bf(b.w);
        *(ushort4_t*)(xbf + i) = *(ushort4_t*)&u[0];
        *(ushort4_t*)(xbf + i + 4) = *(ushort4_t*)&u[4];
    } else {
        // scan for batch b: valid = (pad==0). Outputs (all int32):
        //   cvtab[b][n]  = valid ? slot : -1        (tbl + 0)
        //   pref [b][n]  = #valid in [0,n)          (tbl + 4096)
        //   idxmap[b][s] = orig n of slot s, 2048 for s >= vc   (tbl + 8192)
        //   vcp[b]       = total valid              (tbl + 12288)
        int b = bid - 2816;
        int* cvtab = tbl;
        int* pref = tbl + 4096;
        int* idxmap = tbl + 8192;
        int* vcp = tbl + 12288;
        int lane = t & 63, w4 = t >> 6;
        int base0 = t * 8;
        int v[8], s8 = 0;
        for (int j = 0; j < 8; j++) {
            v[j] = (pad[b * 2048 + base0 + j] == 0) ? 1 : 0;
            s8 += v[j];
        }
        int incl = s8;
        for (int off = 1; off < 64; off <<= 1) {
            int y = __shfl_up(incl, off, 64);
            if (lane >= off) incl += y;
        }
        int excl = incl - s8;
        if (lane == 63) wsum[w4] = incl;
        __syncthreads();
        int wbase = 0;
        for (int ww = 0; ww < 4; ww++) if (ww < w4) wbase += wsum[ww];
        int vcall = wsum[0] + wsum[1] + wsum[2] + wsum[3];
        int run = wbase + excl;
        for (int j = 0; j < 8; j++) {
            int pos = base0 + j;
            pref[b * 2048 + pos] = run;
            cvtab[b * 2048 + pos] = v[j] ? run : -1;
            if (v[j]) idxmap[b * 2048 + run] = pos;
            run += v[j];
        }
        if (t == 0) vcp[b] = vcall;
        for (int s = vcall + t; s < 2048; s += 256) idxmap[b * 2048 + s] = 2048;
    }
}

// ---------- transpose+convert: in fp32 [R][C] -> out bf16 [C][R] ----------
__global__ __launch_bounds__(256) void transpose_f32_bf16(const float* __restrict__ in,
                                                          ushort_t* __restrict__ out,
                                                          int R, int C) {
    __shared__ __align__(16) ushort_t tile[64][65];
    int c0 = blockIdx.x * 64, r0 = blockIdx.y * 64;
    int t = threadIdx.x;
    for (int i = 0; i < 16; i++) {
        int idx = t + i * 256;
        int lr = idx >> 6, lc = idx & 63;
        tile[lr][lc] = f2bf(in[(size_t)(r0 + lr) * C + c0 + lc]);
    }
    __syncthreads();
    for (int i = 0; i < 16; i++) {
        int idx = t + i * 256;
        int lr = idx >> 6, lc = idx & 63;
        out[(size_t)(c0 + lr) * R + r0 + lc] = tile[lc][lr];
    }
}

// ---------- GEMM1: q/k/v = xbf @ wqkvT^T; K/V rows scattered to COMPACT slots ----------
__global__ __launch_bounds__(256) void gemm_qkv(
    const ushort_t* __restrict__ A, const ushort_t* __restrict__ Bt,
    const int* __restrict__ cvtab,
    ushort_t* __restrict__ outQ, ushort_t* __restrict__ outK, ushort_t* __restrict__ outV) {
    const int K = 1024;
    __shared__ __align__(16) ushort_t As[128 * 64];
    __shared__ __align__(16) ushort_t Bs[128 * 64];
    int t = threadIdx.x;
    int w = t >> 6, lane = t & 63;
    int quad = lane >> 4, l15 = lane & 15;
    int wM = w >> 1, wN = w & 1;
    int tM = blockIdx.y * 128, tN = blockIdx.x * 128;

    float4_t acc[4][4];
    for (int i = 0; i < 4; i++)
        for (int j = 0; j < 4; j++) acc[i][j] = (float4_t){0.f, 0.f, 0.f, 0.f};

    int lrow = lane >> 3;
    int lcol8 = (lane & 7) * 8;

    const ushort_t* Abase = A + (size_t)(tM + w * 32) * K;
    const ushort_t* Bbase = Bt + (size_t)(tN + w * 32) * K;

    for (int k0 = 0; k0 < K; k0 += 64) {
        __syncthreads();
        for (int i = 0; i < 4; i++) {
            const ushort_t* ga = Abase + (size_t)(i * 8 + lrow) * K + k0 + lcol8;
            __builtin_amdgcn_global_load_lds((AS1 void*)ga, (AS3 void*)&As[(w * 32 + i * 8) * 64], 16, 0, 0);
            const ushort_t* gb = Bbase + (size_t)(i * 8 + lrow) * K + k0 + lcol8;
            __builtin_amdgcn_global_load_lds((AS1 void*)gb, (AS3 void*)&Bs[(w * 32 + i * 8) * 64], 16, 0, 0);
        }
        __syncthreads();
        for (int kt = 0; kt < 2; kt++) {
            short8 af[4], bf[4];
            for (int m = 0; m < 4; m++)
                af[m] = *(const short8*)&As[(wM * 64 + m * 16 + l15) * 64 + kt * 32 + quad * 8];
            for (int n = 0; n < 4; n++)
                bf[n] = *(const short8*)&Bs[(wN * 64 + n * 16 + l15) * 64 + kt * 32 + quad * 8];
            for (int m = 0; m < 4; m++)
                for (int n = 0; n < 4; n++)
                    acc[m][n] = __builtin_amdgcn_mfma_f32_16x16x32_bf16(af[m], bf[n], acc[m][n], 0, 0, 0);
        }
    }

    for (int m = 0; m < 4; m++) {
        int gm = tM + wM * 64 + m * 16 + quad * 4;
        int cvv[4];
        for (int r = 0; r < 4; r++) cvv[r] = cvtab[gm + r];   // cvtab index == global row
        for (int n = 0; n < 4; n++) {
            int gn = tN + wN * 64 + n * 16 + l15;
            int three = gn >> 10;
            int h = (gn >> 6) & 15;
            int dd = gn & 63;
            for (int r = 0; r < 4; r++) {
                int row = gm + r;
                int b = row >> 11;
                ushort_t val = f2bf(acc[m][n][r]);
                if (three == 0) {
                    int ns = row & 2047;
                    outQ[(((size_t)(b * 16 + h) * 2048 + ns) << 6) + dd] = val;
                } else {
                    int slot = cvv[r];
                    if (slot >= 0) {
                        ushort_t* dst = (three == 1) ? outK : outV;
                        dst[(((size_t)(b * 16 + h) * 2048 + slot) << 6) + dd] = val;
                    }
                }
            }
        }
    }
}

// ---------- flash attention r11: r8 structure over COMPACTED keys ----------
// Padded keys contribute exactly p=0 (fixed-shift softmax), so K/V are compacted
// upstream to valid keys only: chain length halves (32 -> ~ceil(vc_upto(bound)/64)
// ~ 16-17 worst). Inner loop identical to the measured-1.77us/iter r8 loop; padb
// LDS is replaced by the Idx slot->orig table (same 57344 LDS). Causal mask
// compares Idx[slot] (tail slots read 2048 -> always masked -> p = 0 exactly);
// loadV zeroes tail lanes so 0 x garbage can't create NaN in PV.
// Complement mapping g = (y<16)? x : 15-x keeps per-CU pair sums ~uniform.
__global__ __launch_bounds__(512, 4) void attn_kernel(
    const ushort_t* __restrict__ q, const ushort_t* __restrict__ k,
    const ushort_t* __restrict__ v, const int* __restrict__ tbl,
    const int* __restrict__ csp, ushort_t* __restrict__ out) {
    __shared__ __align__(16) ushort_t Ks[2][64 * 64];    // [slot][dd], XOR-swizzled
    __shared__ __align__(16) ushort_t VsT[2][64 * 64];   // [dd][slot], XOR-swizzled
    __shared__ __align__(16) ushort_t Ps[8][16 * 64];    // per-wave P tile
    __shared__ int Idx[2048];                            // slot -> orig key index

    const int* pref = tbl + 4096;
    const int* idxmap = tbl + 8192;
    const int* vcp = tbl + 12288;

    int cs = csp[0];
    int t = threadIdx.x, w = t >> 6, lane = t & 63;
    int quad = lane >> 4, l15 = lane & 15;
    int bh = blockIdx.y;
    int b = bh >> 4, h = bh & 15;
    int g = (blockIdx.y < 16) ? blockIdx.x : 15 - blockIdx.x;
    int q0 = g * 128;
    int rowmin = q0 + w * 16;
    const float c1 = 0.18033688f;    // 0.125 * log2(e)
    const float c2 = -11.541560f;    // -8 * log2(e)

    // keys needed: orig < bound = max(rowmax+1, cs); count them in compact space
    int bound = q0 + 128; if (cs > bound) bound = cs;
    int nvalid = (bound > 2047) ? vcp[b] : pref[b * 2048 + bound];
    int nT = (nvalid + 63) >> 6; if (nT < 1) nT = 1;

    for (int i = 0; i < 4; i++) Idx[t + i * 512] = idxmap[b * 2048 + t + i * 512];

    const ushort_t* qb = q + ((size_t)bh * 2048 + rowmin + l15) * 64;
    short8 qf0 = *(const short8*)(qb + quad * 8);
    short8 qf1 = *(const short8*)(qb + 32 + quad * 8);

    float4_t O[4];
    for (int i = 0; i < 4; i++) O[i] = (float4_t){0.f, 0.f, 0.f, 0.f};
    float ls[4] = {0.f, 0.f, 0.f, 0.f};

    const ushort_t* kbase = k + (size_t)bh * 2048 * 64;
    const ushort_t* vbase = v + (size_t)bh * 2048 * 64;

    int lrow = lane >> 3, lblk = lane & 7;
    int prow = rowmin + quad * 4;
    int sw = l15 & 7;

    short8 vr;   // V register-prefetch (one 8-col strip per wave)
    auto stageK = [&](int it, int buf) {
        int k0 = it * 64;
        const ushort_t* gk = kbase + (size_t)(k0 + w * 8 + lrow) * 64 + ((lblk ^ lrow) * 8);
        __builtin_amdgcn_global_load_lds((AS1 void*)gk, (AS3 void*)&Ks[buf][w * 8 * 64], 16, 0, 0);
    };
    auto loadV = [&](int it) {
        vr = *(const short8*)(vbase + (size_t)(it * 64 + lane) * 64 + w * 8);
        if (it * 64 + lane >= nvalid)
            for (int j = 0; j < 8; j++) vr[j] = 0;
    };

    stageK(0, 0);
    loadV(0);

    for (int it = 0; it < nT; it++) {
        int cur = it & 1, nxt = cur ^ 1;
        for (int j = 0; j < 8; j++) {
            int sl = ((lrow ^ j) * 8) + lblk;
            VsT[cur][(w * 8 + j) * 64 + sl] = (ushort_t)vr[j];
        }
        __syncthreads();  // drains this tile's K glds; VsT[cur] + Idx visible
        if (it + 1 < nT) {
            stageK(it + 1, nxt);
            loadV(it + 1);
        }

        int k0 = it * 64;
        int omin = Idx[k0];
        // tile fully masked for this wave? (min orig > all rows and >= cs)
        bool act = (omin <= rowmin + 15) || (omin < cs);
        if (act) {
            int omax = Idx[k0 + 63];
            bool needC = (omax > rowmin) && (omax >= cs);

            short8 kf0[4], kf1[4];
            for (int ks = 0; ks < 4; ks++) {
                const ushort_t* krow = &Ks[cur][(ks * 16 + l15) * 64];
                kf0[ks] = *(const short8*)(krow + (quad ^ sw) * 8);
                kf1[ks] = *(const short8*)(krow + ((4 + quad) ^ sw) * 8);
            }

            float4_t s[4];
            for (int ks = 0; ks < 4; ks++) {
                float4_t a = (float4_t){0.f, 0.f, 0.f, 0.f};
                a = __builtin_amdgcn_mfma_f32_16x16x32_bf16(qf0, kf0[ks], a, 0, 0, 0);
                a = __builtin_amdgcn_mfma_f32_16x16x32_bf16(qf1, kf1[ks], a, 0, 0, 0);
                s[ks] = a;
            }
            for (int ks = 0; ks < 4; ks++) {
                int key = Idx[k0 + ks * 16 + l15];   // orig index; 2048 for tail
                for (int r = 0; r < 4; r++) {
                    float arg = s[ks][r] * c1 + c2;
                    if (needC && (key > prow + r) && (key >= cs)) arg = -1e38f;
                    float p = __builtin_amdgcn_exp2f(arg);
                    ls[r] += p;
                    int row = quad * 4 + r;
                    Ps[w][row * 64 + (((ks * 2 + (l15 >> 3)) ^ (row & 7)) * 8) + (l15 & 7)] = f2bf_trunc(p);
                }
            }

            short8 vf0[4], vf1[4];
            for (int n = 0; n < 4; n++) {
                const ushort_t* vrow = &VsT[cur][(n * 16 + l15) * 64];
                vf0[n] = *(const short8*)(vrow + (quad ^ sw) * 8);
                vf1[n] = *(const short8*)(vrow + ((4 + quad) ^ sw) * 8);
            }
            const ushort_t* prl = &Ps[w][l15 * 64];
            short8 pf0 = *(const short8*)(prl + (quad ^ sw) * 8);
            short8 pf1 = *(const short8*)(prl + ((4 + quad) ^ sw) * 8);
            for (int n = 0; n < 4; n++) {
                O[n] = __builtin_amdgcn_mfma_f32_16x16x32_bf16(pf0, vf0[n], O[n], 0, 0, 0);
                O[n] = __builtin_amdgcn_mfma_f32_16x16x32_bf16(pf1, vf1[n], O[n], 0, 0, 0);
            }
        }
    }

    for (int r = 0; r < 4; r++) {
        float l = ls[r];
        l += __shfl_xor(l, 1, 64); l += __shfl_xor(l, 2, 64);
        l += __shfl_xor(l, 4, 64); l += __shfl_xor(l, 8, 64);
        float inv = l > 0.f ? 1.f / l : 0.f;
        int row = rowmin + quad * 4 + r;
        size_t ob = ((size_t)b * 2048 + row) * 1024 + h * 64;
        for (int n = 0; n < 4; n++)
            out[ob + n * 16 + l15] = f2bf(O[n][r] * inv);
    }
}

// ---------- GEMM2: out = ao @ wprojT^T + bias (bf16 A via glds, fp32 out) ----------
__global__ __launch_bounds__(256) void gemm_out_k(
    const ushort_t* __restrict__ A, const ushort_t* __restrict__ Bt,
    const float* __restrict__ bias, float* __restrict__ outC) {
    const int K = 1024, N = 1024;
    __shared__ __align__(16) ushort_t As[128 * 64];
    __shared__ __align__(16) ushort_t Bs[128 * 64];
    int t = threadIdx.x;
    int w = t >> 6, lane = t & 63;
    int quad = lane >> 4, l15 = lane & 15;
    int wM = w >> 1, wN = w & 1;
    int tM = blockIdx.y * 128, tN = blockIdx.x * 128;

    float4_t acc[4][4];
    for (int i = 0; i < 4; i++)
        for (int j = 0; j < 4; j++) acc[i][j] = (float4_t){0.f, 0.f, 0.f, 0.f};

    int lrow = lane >> 3;
    int lcol8 = (lane & 7) * 8;

    const ushort_t* Abase = A + (size_t)(tM + w * 32) * K;
    const ushort_t* Bbase = Bt + (size_t)(tN + w * 32) * K;

    for (int k0 = 0; k0 < K; k0 += 64) {
        __syncthreads();
        for (int i = 0; i < 4; i++) {
            const ushort_t* ga = Abase + (size_t)(i * 8 + lrow) * K + k0 + lcol8;
            __builtin_amdgcn_global_load_lds((AS1 void*)ga, (AS3 void*)&As[(w * 32 + i * 8) * 64], 16, 0, 0);
            const ushort_t* gb = Bbase + (size_t)(i * 8 + lrow) * K + k0 + lcol8;
            __builtin_amdgcn_global_load_lds((AS1 void*)gb, (AS3 void*)&Bs[(w * 32 + i * 8) * 64], 16, 0, 0);
        }
        __syncthreads();
        for (int kt = 0; kt < 2; kt++) {
            short8 af[4], bf[4];
            for (int m = 0; m < 4; m++)
                af[m] = *(const short8*)&As[(wM * 64 + m * 16 + l15) * 64 + kt * 32 + quad * 8];
            for (int n = 0; n < 4; n++)
                bf[n] = *(const short8*)&Bs[(wN * 64 + n * 16 + l15) * 64 + kt * 32 + quad * 8];
            for (int m = 0; m < 4; m++)
                for (int n = 0; n < 4; n++)
                    acc[m][n] = __builtin_amdgcn_mfma_f32_16x16x32_bf16(af[m], bf[n], acc[m][n], 0, 0, 0);
        }
    }

    for (int m = 0; m < 4; m++) {
        int gm = tM + wM * 64 + m * 16 + quad * 4;
        for (int n = 0; n < 4; n++) {
            int gn = tN + wN * 64 + n * 16 + l15;
            float bv = bias[gn];
            for (int r = 0; r < 4; r++)
                outC[(size_t)(gm + r) * N + gn] = acc[m][n][r] + bv;
        }
    }
}

extern "C" void kernel_launch(void* const* d_in, const int* in_sizes, int n_in,
                              void* d_out, int out_size, void* d_ws, size_t ws_size,
                              hipStream_t stream) {
    const float* x = (const float*)d_in[0];
    const int* pad = (const int*)d_in[1];
    const int* cs = (const int*)d_in[2];
    const float* wqkv = (const float*)d_in[3];
    const float* wproj = (const float*)d_in[4];
    const float* bproj = (const float*)d_in[5];
    float* out = (float*)d_out;

    // ws (peak 32 MB, lifetimes audited):
    //   q[0,8M) k[8,16M) v[16,24M)        gemm1 -> attn (k/v compacted; tail rows garbage,
    //                                     handled by Idx mask + loadV zeroing)
    //   wqkvT[24,30M)                     prep -> gemm1 (dies)
    //   ao bf16 [24,32M)                  attn -> gemm2 (over dead wqkvT)
    //   wprojT[0,2M)                      transposed AFTER attn (over dead q)
    // d_out (16MB): xbf bf16 [0,8M) prep -> gemm1 (dies);
    //   scan tables int32 @8M: cvtab[2][2048], pref[2][2048], idxmap[2][2048], vcp[2]
    //   (written by prep scan blocks; read by gemm1 (cvtab) and attn (pref/idxmap/vcp);
    //   dead before gemm2 overwrites d_out with the final fp32 output).
    ushort_t* ws = (ushort_t*)d_ws;
    ushort_t* qws = ws;
    ushort_t* kws = ws + (size_t)4194304;
    ushort_t* vws = ws + (size_t)8388608;
    ushort_t* wqkvT = ws + (size_t)12582912;
    ushort_t* aows = ws + (size_t)12582912;
    ushort_t* wprojT = ws;
    ushort_t* xbf = (ushort_t*)d_out;
    int* tbl = (int*)((char*)d_out + 8388608);

    prep_fused<<<2818, 256, 0, stream>>>(wqkv, x, pad, wqkvT, xbf, tbl);
    gemm_qkv<<<dim3(24, 32), 256, 0, stream>>>(xbf, wqkvT, tbl, qws, kws, vws);
    attn_kernel<<<dim3(16, 32), 512, 0, stream>>>(qws, kws, vws, tbl, cs, aows);
    transpose_f32_bf16<<<dim3(16, 16), 256, 0, stream>>>(wproj, wprojT, 1024, 1024);
    gemm_out_k<<<dim3(8, 32), 256, 0, stream>>>(aows, wprojT, bproj, out);
}

// Round 8
// 191.050 us; speedup vs baseline: 1.3521x; 1.0473x over previous
//
#include <hip/hip_runtime.h>
#include <stdint.h>

typedef unsigned short ushort_t;
typedef __attribute__((ext_vector_type(4))) unsigned short ushort4_t;
typedef __attribute__((ext_vector_type(8))) short short8;
typedef __attribute__((ext_vector_type(4))) float float4_t;

#define AS1 __attribute__((address_space(1)))
#define AS3 __attribute__((address_space(3)))

__device__ inline ushort_t f2bf(float f) {
    unsigned x = __builtin_bit_cast(unsigned, f);
    unsigned r = x + 0x7fffu + ((x >> 16) & 1u);
    return (ushort_t)(r >> 16);
}
__device__ inline ushort_t f2bf_trunc(float f) {
    return (ushort_t)(__builtin_bit_cast(unsigned, f) >> 16);
}

// ---------- fused prep: transpose W_qkv + convert x + pad-mask scan ----------
// blocks [0,768): wqkv 1024x3072 -> T bf16; [768,2816): x fp32 -> bf16;
// [2816,2818): per-batch prefix scan of padding mask -> cvtab/pref/idxmap/vcp.
__global__ __launch_bounds__(256) void prep_fused(
    const float* __restrict__ wqkv, const float* __restrict__ x,
    const int* __restrict__ pad,
    ushort_t* __restrict__ wqkvT, ushort_t* __restrict__ xbf,
    int* __restrict__ tbl) {
    __shared__ __align__(16) ushort_t tile[64][65];
    __shared__ int wsum[4];
    int bid = blockIdx.x, t = threadIdx.x;
    if (bid < 768) {
        int bx = bid % 48, by = bid / 48;
        int c0 = bx * 64, r0 = by * 64;
        for (int i = 0; i < 16; i++) {
            int idx = t + i * 256;
            int lr = idx >> 6, lc = idx & 63;
            tile[lr][lc] = f2bf(wqkv[(size_t)(r0 + lr) * 3072 + c0 + lc]);
        }
        __syncthreads();
        for (int i = 0; i < 16; i++) {
            int idx = t + i * 256;
            int lr = idx >> 6, lc = idx & 63;
            wqkvT[(size_t)(c0 + lr) * 1024 + r0 + lc] = tile[lc][lr];
        }
    } else if (bid < 2816) {
        size_t i = ((size_t)(bid - 768) * 256 + t) * 8;
        float4_t a = *(const float4_t*)(x + i);
        float4_t b = *(const float4_t*)(x + i + 4);
        ushort_t u[8];
        u[0] = f2bf(a.x); u[1] = f2bf(a.y); u[2] = f2bf(a.z); u[3] = f2bf(a.w);
        u[4] = f2bf(b.x); u[5] = f2bf(b.y); u[6] = f2bf(b.z); u[7] = f2bf(b.w);
        *(ushort4_t*)(xbf + i) = *(ushort4_t*)&u[0];
        *(ushort4_t*)(xbf + i + 4) = *(ushort4_t*)&u[4];
    } else {
        // scan for batch b: valid = (pad==0). Outputs (all int32):
        //   cvtab[b][n]  = valid ? slot : -1        (tbl + 0)
        //   pref [b][n]  = #valid in [0,n)          (tbl + 4096)
        //   idxmap[b][s] = orig n of slot s, 2048 for s >= vc   (tbl + 8192)
        //   vcp[b]       = total valid              (tbl + 12288)
        int b = bid - 2816;
        int* cvtab = tbl;
        int* pref = tbl + 4096;
        int* idxmap = tbl + 8192;
        int* vcp = tbl + 12288;
        int lane = t & 63, w4 = t >> 6;
        int base0 = t * 8;
        int v[8], s8 = 0;
        for (int j = 0; j < 8; j++) {
            v[j] = (pad[b * 2048 + base0 + j] == 0) ? 1 : 0;
            s8 += v[j];
        }
        int incl = s8;
        for (int off = 1; off < 64; off <<= 1) {
            int y = __shfl_up(incl, off, 64);
            if (lane >= off) incl += y;
        }
        int excl = incl - s8;
        if (lane == 63) wsum[w4] = incl;
        __syncthreads();
        int wbase = 0;
        for (int ww = 0; ww < 4; ww++) if (ww < w4) wbase += wsum[ww];
        int vcall = wsum[0] + wsum[1] + wsum[2] + wsum[3];
        int run = wbase + excl;
        for (int j = 0; j < 8; j++) {
            int pos = base0 + j;
            pref[b * 2048 + pos] = run;
            cvtab[b * 2048 + pos] = v[j] ? run : -1;
            if (v[j]) idxmap[b * 2048 + run] = pos;
            run += v[j];
        }
        if (t == 0) vcp[b] = vcall;
        for (int s = vcall + t; s < 2048; s += 256) idxmap[b * 2048 + s] = 2048;
    }
}

// ---------- transpose+convert: in fp32 [R][C] -> out bf16 [C][R] ----------
__global__ __launch_bounds__(256) void transpose_f32_bf16(const float* __restrict__ in,
                                                          ushort_t* __restrict__ out,
                                                          int R, int C) {
    __shared__ __align__(16) ushort_t tile[64][65];
    int c0 = blockIdx.x * 64, r0 = blockIdx.y * 64;
    int t = threadIdx.x;
    for (int i = 0; i < 16; i++) {
        int idx = t + i * 256;
        int lr = idx >> 6, lc = idx & 63;
        tile[lr][lc] = f2bf(in[(size_t)(r0 + lr) * C + c0 + lc]);
    }
    __syncthreads();
    for (int i = 0; i < 16; i++) {
        int idx = t + i * 256;
        int lr = idx >> 6, lc = idx & 63;
        out[(size_t)(c0 + lr) * R + r0 + lc] = tile[lc][lr];
    }
}

// ---------- GEMM1 r12: Q for all rows; K/V only for valid (compacted) rows ----------
// grid (24,32): x<8 -> Q N-tile (cols [0,1024)); x>=8 -> KV N-tile (cols [1024,3072)).
// y for Q: global-row tile y*128 (both batches, row>>11 = b). y for KV: b = y>>4,
// compact-slot tile (y&15)*128; blocks with slot-base >= vc[b] exit before any
// barrier (~44% of KV blocks at ~50% pad density). A-rows for KV are gathered via
// idxmap (4 per-thread lookups hoisted before the K-loop); the 2-phase glds K-loop
// body is unchanged from the proven kernel. Saves ~29% of GEMM FLOPs vs computing
// K/V for padded rows and discarding them (r11).
__global__ __launch_bounds__(256) void gemm_qkv(
    const ushort_t* __restrict__ A, const ushort_t* __restrict__ Bt,
    const int* __restrict__ tbl,
    ushort_t* __restrict__ outQ, ushort_t* __restrict__ outK, ushort_t* __restrict__ outV) {
    const int K = 1024;
    __shared__ __align__(16) ushort_t As[128 * 64];
    __shared__ __align__(16) ushort_t Bs[128 * 64];
    const int* idxmap = tbl + 8192;
    const int* vcp = tbl + 12288;
    int t = threadIdx.x;
    int w = t >> 6, lane = t & 63;
    int quad = lane >> 4, l15 = lane & 15;
    int wM = w >> 1, wN = w & 1;
    int lrow = lane >> 3;
    int lcol8 = (lane & 7) * 8;

    bool isQ = blockIdx.x < 8;
    int b = 0, m0, vc = 0, tNr;
    size_t arow[4];
    if (isQ) {
        tNr = blockIdx.x * 128;              // B rows (= output cols) [0,1024)
        m0 = blockIdx.y * 128;               // global row base [0,4096)
        for (int i = 0; i < 4; i++)
            arow[i] = (size_t)(m0 + w * 32 + i * 8 + lrow) * K;
    } else {
        tNr = 1024 + (blockIdx.x - 8) * 128; // B rows [1024,3072)
        b = blockIdx.y >> 4;
        vc = vcp[b];
        m0 = (blockIdx.y & 15) * 128;        // compact slot base [0,2048)
        if (m0 >= vc) return;                // whole tile is tail -> no work
        for (int i = 0; i < 4; i++) {
            int slot = m0 + w * 32 + i * 8 + lrow;
            int orig = idxmap[b * 2048 + slot];   // 2048 for tail (A read garbage, in-bounds; stores guarded)
            arow[i] = (size_t)(b * 2048 + orig) * K;
        }
    }

    float4_t acc[4][4];
    for (int i = 0; i < 4; i++)
        for (int j = 0; j < 4; j++) acc[i][j] = (float4_t){0.f, 0.f, 0.f, 0.f};

    const ushort_t* Bbase = Bt + (size_t)(tNr + w * 32) * K;

    for (int k0 = 0; k0 < K; k0 += 64) {
        __syncthreads();
        for (int i = 0; i < 4; i++) {
            const ushort_t* ga = A + arow[i] + k0 + lcol8;
            __builtin_amdgcn_global_load_lds((AS1 void*)ga, (AS3 void*)&As[(w * 32 + i * 8) * 64], 16, 0, 0);
            const ushort_t* gb = Bbase + (size_t)(i * 8 + lrow) * K + k0 + lcol8;
            __builtin_amdgcn_global_load_lds((AS1 void*)gb, (AS3 void*)&Bs[(w * 32 + i * 8) * 64], 16, 0, 0);
        }
        __syncthreads();
        for (int kt = 0; kt < 2; kt++) {
            short8 af[4], bf[4];
            for (int m = 0; m < 4; m++)
                af[m] = *(const short8*)&As[(wM * 64 + m * 16 + l15) * 64 + kt * 32 + quad * 8];
            for (int n = 0; n < 4; n++)
                bf[n] = *(const short8*)&Bs[(wN * 64 + n * 16 + l15) * 64 + kt * 32 + quad * 8];
            for (int m = 0; m < 4; m++)
                for (int n = 0; n < 4; n++)
                    acc[m][n] = __builtin_amdgcn_mfma_f32_16x16x32_bf16(af[m], bf[n], acc[m][n], 0, 0, 0);
        }
    }

    for (int m = 0; m < 4; m++) {
        int lm = wM * 64 + m * 16 + quad * 4;     // local row within the 128-row tile
        for (int n = 0; n < 4; n++) {
            int lnc = wN * 64 + n * 16 + l15;     // local col within the 128-col tile
            if (isQ) {
                int gn = tNr + lnc;               // [0,1024)
                int h = gn >> 6, dd = gn & 63;
                for (int r = 0; r < 4; r++) {
                    int row = m0 + lm + r;
                    int bb = row >> 11, ns = row & 2047;
                    outQ[(((size_t)(bb * 16 + h) * 2048 + ns) << 6) + dd] = f2bf(acc[m][n][r]);
                }
            } else {
                int gnc = tNr - 1024 + lnc;       // [0,2048): K then V
                ushort_t* dst = (gnc < 1024) ? outK : outV;
                int hh = (gnc >> 6) & 15, dd = gnc & 63;
                for (int r = 0; r < 4; r++) {
                    int slot = m0 + lm + r;
                    if (slot < vc)
                        dst[(((size_t)(b * 16 + hh) * 2048 + slot) << 6) + dd] = f2bf(acc[m][n][r]);
                }
            }
        }
    }
}

// ---------- flash attention r11: r8 structure over COMPACTED keys (unchanged, verified) ----------
__global__ __launch_bounds__(512, 4) void attn_kernel(
    const ushort_t* __restrict__ q, const ushort_t* __restrict__ k,
    const ushort_t* __restrict__ v, const int* __restrict__ tbl,
    const int* __restrict__ csp, ushort_t* __restrict__ out) {
    __shared__ __align__(16) ushort_t Ks[2][64 * 64];    // [slot][dd], XOR-swizzled
    __shared__ __align__(16) ushort_t VsT[2][64 * 64];   // [dd][slot], XOR-swizzled
    __shared__ __align__(16) ushort_t Ps[8][16 * 64];    // per-wave P tile
    __shared__ int Idx[2048];                            // slot -> orig key index

    const int* pref = tbl + 4096;
    const int* idxmap = tbl + 8192;
    const int* vcp = tbl + 12288;

    int cs = csp[0];
    int t = threadIdx.x, w = t >> 6, lane = t & 63;
    int quad = lane >> 4, l15 = lane & 15;
    int bh = blockIdx.y;
    int b = bh >> 4, h = bh & 15;
    int g = (blockIdx.y < 16) ? blockIdx.x : 15 - blockIdx.x;
    int q0 = g * 128;
    int rowmin = q0 + w * 16;
    const float c1 = 0.18033688f;    // 0.125 * log2(e)
    const float c2 = -11.541560f;    // -8 * log2(e)

    // keys needed: orig < bound = max(rowmax+1, cs); count them in compact space
    int bound = q0 + 128; if (cs > bound) bound = cs;
    int nvalid = (bound > 2047) ? vcp[b] : pref[b * 2048 + bound];
    int nT = (nvalid + 63) >> 6; if (nT < 1) nT = 1;

    for (int i = 0; i < 4; i++) Idx[t + i * 512] = idxmap[b * 2048 + t + i * 512];

    const ushort_t* qb = q + ((size_t)bh * 2048 + rowmin + l15) * 64;
    short8 qf0 = *(const short8*)(qb + quad * 8);
    short8 qf1 = *(const short8*)(qb + 32 + quad * 8);

    float4_t O[4];
    for (int i = 0; i < 4; i++) O[i] = (float4_t){0.f, 0.f, 0.f, 0.f};
    float ls[4] = {0.f, 0.f, 0.f, 0.f};

    const ushort_t* kbase = k + (size_t)bh * 2048 * 64;
    const ushort_t* vbase = v + (size_t)bh * 2048 * 64;

    int lrow = lane >> 3, lblk = lane & 7;
    int prow = rowmin + quad * 4;
    int sw = l15 & 7;

    short8 vr;   // V register-prefetch (one 8-col strip per wave)
    auto stageK = [&](int it, int buf) {
        int k0 = it * 64;
        const ushort_t* gk = kbase + (size_t)(k0 + w * 8 + lrow) * 64 + ((lblk ^ lrow) * 8);
        __builtin_amdgcn_global_load_lds((AS1 void*)gk, (AS3 void*)&Ks[buf][w * 8 * 64], 16, 0, 0);
    };
    auto loadV = [&](int it) {
        vr = *(const short8*)(vbase + (size_t)(it * 64 + lane) * 64 + w * 8);
        if (it * 64 + lane >= nvalid)
            for (int j = 0; j < 8; j++) vr[j] = 0;
    };

    stageK(0, 0);
    loadV(0);

    for (int it = 0; it < nT; it++) {
        int cur = it & 1, nxt = cur ^ 1;
        for (int j = 0; j < 8; j++) {
            int sl = ((lrow ^ j) * 8) + lblk;
            VsT[cur][(w * 8 + j) * 64 + sl] = (ushort_t)vr[j];
        }
        __syncthreads();  // drains this tile's K glds; VsT[cur] + Idx visible
        if (it + 1 < nT) {
            stageK(it + 1, nxt);
            loadV(it + 1);
        }

        int k0 = it * 64;
        int omin = Idx[k0];
        // tile fully masked for this wave? (min orig > all rows and >= cs)
        bool act = (omin <= rowmin + 15) || (omin < cs);
        if (act) {
            int omax = Idx[k0 + 63];
            bool needC = (omax > rowmin) && (omax >= cs);

            short8 kf0[4], kf1[4];
            for (int ks = 0; ks < 4; ks++) {
                const ushort_t* krow = &Ks[cur][(ks * 16 + l15) * 64];
                kf0[ks] = *(const short8*)(krow + (quad ^ sw) * 8);
                kf1[ks] = *(const short8*)(krow + ((4 + quad) ^ sw) * 8);
            }

            float4_t s[4];
            for (int ks = 0; ks < 4; ks++) {
                float4_t a = (float4_t){0.f, 0.f, 0.f, 0.f};
                a = __builtin_amdgcn_mfma_f32_16x16x32_bf16(qf0, kf0[ks], a, 0, 0, 0);
                a = __builtin_amdgcn_mfma_f32_16x16x32_bf16(qf1, kf1[ks], a, 0, 0, 0);
                s[ks] = a;
            }
            for (int ks = 0; ks < 4; ks++) {
                int key = Idx[k0 + ks * 16 + l15];   // orig index; 2048 for tail
                for (int r = 0; r < 4; r++) {
                    float arg = s[ks][r] * c1 + c2;
                    if (needC && (key > prow + r) && (key >= cs)) arg = -1e38f;
                    float p = __builtin_amdgcn_exp2f(arg);
                    ls[r] += p;
                    int row = quad * 4 + r;
                    Ps[w][row * 64 + (((ks * 2 + (l15 >> 3)) ^ (row & 7)) * 8) + (l15 & 7)] = f2bf_trunc(p);
                }
            }

            short8 vf0[4], vf1[4];
            for (int n = 0; n < 4; n++) {
                const ushort_t* vrow = &VsT[cur][(n * 16 + l15) * 64];
                vf0[n] = *(const short8*)(vrow + (quad ^ sw) * 8);
                vf1[n] = *(const short8*)(vrow + ((4 + quad) ^ sw) * 8);
            }
            const ushort_t* prl = &Ps[w][l15 * 64];
            short8 pf0 = *(const short8*)(prl + (quad ^ sw) * 8);
            short8 pf1 = *(const short8*)(prl + ((4 + quad) ^ sw) * 8);
            for (int n = 0; n < 4; n++) {
                O[n] = __builtin_amdgcn_mfma_f32_16x16x32_bf16(pf0, vf0[n], O[n], 0, 0, 0);
                O[n] = __builtin_amdgcn_mfma_f32_16x16x32_bf16(pf1, vf1[n], O[n], 0, 0, 0);
            }
        }
    }

    for (int r = 0; r < 4; r++) {
        float l = ls[r];
        l += __shfl_xor(l, 1, 64); l += __shfl_xor(l, 2, 64);
        l += __shfl_xor(l, 4, 64); l += __shfl_xor(l, 8, 64);
        float inv = l > 0.f ? 1.f / l : 0.f;
        int row = rowmin + quad * 4 + r;
        size_t ob = ((size_t)b * 2048 + row) * 1024 + h * 64;
        for (int n = 0; n < 4; n++)
            out[ob + n * 16 + l15] = f2bf(O[n][r] * inv);
    }
}

// ---------- GEMM2: out = ao @ wprojT^T + bias (bf16 A via glds, fp32 out) ----------
__global__ __launch_bounds__(256) void gemm_out_k(
    const ushort_t* __restrict__ A, const ushort_t* __restrict__ Bt,
    const float* __restrict__ bias, float* __restrict__ outC) {
    const int K = 1024, N = 1024;
    __shared__ __align__(16) ushort_t As[128 * 64];
    __shared__ __align__(16) ushort_t Bs[128 * 64];
    int t = threadIdx.x;
    int w = t >> 6, lane = t & 63;
    int quad = lane >> 4, l15 = lane & 15;
    int wM = w >> 1, wN = w & 1;
    int tM = blockIdx.y * 128, tN = blockIdx.x * 128;

    float4_t acc[4][4];
    for (int i = 0; i < 4; i++)
        for (int j = 0; j < 4; j++) acc[i][j] = (float4_t){0.f, 0.f, 0.f, 0.f};

    int lrow = lane >> 3;
    int lcol8 = (lane & 7) * 8;

    const ushort_t* Abase = A + (size_t)(tM + w * 32) * K;
    const ushort_t* Bbase = Bt + (size_t)(tN + w * 32) * K;

    for (int k0 = 0; k0 < K; k0 += 64) {
        __syncthreads();
        for (int i = 0; i < 4; i++) {
            const ushort_t* ga = Abase + (size_t)(i * 8 + lrow) * K + k0 + lcol8;
            __builtin_amdgcn_global_load_lds((AS1 void*)ga, (AS3 void*)&As[(w * 32 + i * 8) * 64], 16, 0, 0);
            const ushort_t* gb = Bbase + (size_t)(i * 8 + lrow) * K + k0 + lcol8;
            __builtin_amdgcn_global_load_lds((AS1 void*)gb, (AS3 void*)&Bs[(w * 32 + i * 8) * 64], 16, 0, 0);
        }
        __syncthreads();
        for (int kt = 0; kt < 2; kt++) {
            short8 af[4], bf[4];
            for (int m = 0; m < 4; m++)
                af[m] = *(const short8*)&As[(wM * 64 + m * 16 + l15) * 64 + kt * 32 + quad * 8];
            for (int n = 0; n < 4; n++)
                bf[n] = *(const short8*)&Bs[(wN * 64 + n * 16 + l15) * 64 + kt * 32 + quad * 8];
            for (int m = 0; m < 4; m++)
                for (int n = 0; n < 4; n++)
                    acc[m][n] = __builtin_amdgcn_mfma_f32_16x16x32_bf16(af[m], bf[n], acc[m][n], 0, 0, 0);
        }
    }

    for (int m = 0; m < 4; m++) {
        int gm = tM + wM * 64 + m * 16 + quad * 4;
        for (int n = 0; n < 4; n++) {
            int gn = tN + wN * 64 + n * 16 + l15;
            float bv = bias[gn];
            for (int r = 0; r < 4; r++)
                outC[(size_t)(gm + r) * N + gn] = acc[m][n][r] + bv;
        }
    }
}

extern "C" void kernel_launch(void* const* d_in, const int* in_sizes, int n_in,
                              void* d_out, int out_size, void* d_ws, size_t ws_size,
                              hipStream_t stream) {
    const float* x = (const float*)d_in[0];
    const int* pad = (const int*)d_in[1];
    const int* cs = (const int*)d_in[2];
    const float* wqkv = (const float*)d_in[3];
    const float* wproj = (const float*)d_in[4];
    const float* bproj = (const float*)d_in[5];
    float* out = (float*)d_out;

    // ws (peak 32 MB, lifetimes audited):
    //   q[0,8M) k[8,16M) v[16,24M)        gemm1 -> attn (k/v compacted; tail rows garbage,
    //                                     handled by Idx mask + loadV zeroing)
    //   wqkvT[24,30M)                     prep -> gemm1 (dies)
    //   ao bf16 [24,32M)                  attn -> gemm2 (over dead wqkvT)
    //   wprojT[0,2M)                      transposed AFTER attn (over dead q)
    // d_out (16MB): xbf bf16 [0,8M) prep -> gemm1 (dies);
    //   scan tables int32 @8M: cvtab[2][2048], pref[2][2048], idxmap[2][2048], vcp[2]
    //   (written by prep scan blocks; read by gemm1 (idxmap/vcp) and attn
    //   (pref/idxmap/vcp); dead before gemm2 overwrites d_out with final fp32 out).
    ushort_t* ws = (ushort_t*)d_ws;
    ushort_t* qws = ws;
    ushort_t* kws = ws + (size_t)4194304;
    ushort_t* vws = ws + (size_t)8388608;
    ushort_t* wqkvT = ws + (size_t)12582912;
    ushort_t* aows = ws + (size_t)12582912;
    ushort_t* wprojT = ws;
    ushort_t* xbf = (ushort_t*)d_out;
    int* tbl = (int*)((char*)d_out + 8388608);

    prep_fused<<<2818, 256, 0, stream>>>(wqkv, x, pad, wqkvT, xbf, tbl);
    gemm_qkv<<<dim3(24, 32), 256, 0, stream>>>(xbf, wqkvT, tbl, qws, kws, vws);
    attn_kernel<<<dim3(16, 32), 512, 0, stream>>>(qws, kws, vws, tbl, cs, aows);
    transpose_f32_bf16<<<dim3(16, 16), 256, 0, stream>>>(wproj, wprojT, 1024, 1024);
    gemm_out_k<<<dim3(8, 32), 256, 0, stream>>>(aows, wprojT, bproj, out);
}

// Round 9
// 175.326 us; speedup vs baseline: 1.4733x; 1.0897x over previous
//
#include <hip/hip_runtime.h>
#include <stdint.h>

typedef unsigned short ushort_t;
typedef __attribute__((ext_vector_type(4))) unsigned short ushort4_t;
typedef __attribute__((ext_vector_type(8))) short short8;
typedef __attribute__((ext_vector_type(4))) float float4_t;

#define AS1 __attribute__((address_space(1)))
#define AS3 __attribute__((address_space(3)))

__device__ inline ushort_t f2bf(float f) {
    unsigned x = __builtin_bit_cast(unsigned, f);
    unsigned r = x + 0x7fffu + ((x >> 16) & 1u);
    return (ushort_t)(r >> 16);
}
__device__ inline ushort_t f2bf_trunc(float f) {
    return (ushort_t)(__builtin_bit_cast(unsigned, f) >> 16);
}

// ---------- fused prep: transpose W_qkv + convert x + pad scan (+ optional wproj^T) ----------
// blocks [0,768): wqkv 1024x3072 -> T bf16; [768,2816): x fp32 -> bf16;
// [2816,2818): per-batch prefix scan of padding mask -> cvtab/pref/idxmap/vcp;
// [2818,3074) (fused mode only): wproj 1024x1024 -> T bf16.
__global__ __launch_bounds__(256) void prep_fused(
    const float* __restrict__ wqkv, const float* __restrict__ x,
    const int* __restrict__ pad, const float* __restrict__ wproj,
    ushort_t* __restrict__ wqkvT, ushort_t* __restrict__ xbf,
    int* __restrict__ tbl, ushort_t* __restrict__ wprojT) {
    __shared__ __align__(16) ushort_t tile[64][65];
    __shared__ int wsum[4];
    int bid = blockIdx.x, t = threadIdx.x;
    if (bid < 768) {
        int bx = bid % 48, by = bid / 48;
        int c0 = bx * 64, r0 = by * 64;
        for (int i = 0; i < 16; i++) {
            int idx = t + i * 256;
            int lr = idx >> 6, lc = idx & 63;
            tile[lr][lc] = f2bf(wqkv[(size_t)(r0 + lr) * 3072 + c0 + lc]);
        }
        __syncthreads();
        for (int i = 0; i < 16; i++) {
            int idx = t + i * 256;
            int lr = idx >> 6, lc = idx & 63;
            wqkvT[(size_t)(c0 + lr) * 1024 + r0 + lc] = tile[lc][lr];
        }
    } else if (bid < 2816) {
        size_t i = ((size_t)(bid - 768) * 256 + t) * 8;
        float4_t a = *(const float4_t*)(x + i);
        float4_t b = *(const float4_t*)(x + i + 4);
        ushort_t u[8];
        u[0] = f2bf(a.x); u[1] = f2bf(a.y); u[2] = f2bf(a.z); u[3] = f2bf(a.w);
        u[4] = f2bf(b.x); u[5] = f2bf(b.y); u[6] = f2bf(b.z); u[7] = f2bf(b.w);
        *(ushort4_t*)(xbf + i) = *(ushort4_t*)&u[0];
        *(ushort4_t*)(xbf + i + 4) = *(ushort4_t*)&u[4];
    } else if (bid < 2818) {
        // scan for batch b: valid = (pad==0). Outputs (all int32):
        //   cvtab[b][n]  = valid ? slot : -1        (tbl + 0)
        //   pref [b][n]  = #valid in [0,n)          (tbl + 4096)
        //   idxmap[b][s] = orig n of slot s, 2048 for s >= vc   (tbl + 8192)
        //   vcp[b]       = total valid              (tbl + 12288)
        int b = bid - 2816;
        int* cvtab = tbl;
        int* pref = tbl + 4096;
        int* idxmap = tbl + 8192;
        int* vcp = tbl + 12288;
        int lane = t & 63, w4 = t >> 6;
        int base0 = t * 8;
        int v[8], s8 = 0;
        for (int j = 0; j < 8; j++) {
            v[j] = (pad[b * 2048 + base0 + j] == 0) ? 1 : 0;
            s8 += v[j];
        }
        int incl = s8;
        for (int off = 1; off < 64; off <<= 1) {
            int y = __shfl_up(incl, off, 64);
            if (lane >= off) incl += y;
        }
        int excl = incl - s8;
        if (lane == 63) wsum[w4] = incl;
        __syncthreads();
        int wbase = 0;
        for (int ww = 0; ww < 4; ww++) if (ww < w4) wbase += wsum[ww];
        int vcall = wsum[0] + wsum[1] + wsum[2] + wsum[3];
        int run = wbase + excl;
        for (int j = 0; j < 8; j++) {
            int pos = base0 + j;
            pref[b * 2048 + pos] = run;
            cvtab[b * 2048 + pos] = v[j] ? run : -1;
            if (v[j]) idxmap[b * 2048 + run] = pos;
            run += v[j];
        }
        if (t == 0) vcp[b] = vcall;
        for (int s = vcall + t; s < 2048; s += 256) idxmap[b * 2048 + s] = 2048;
    } else {
        // fused wproj transpose: 1024x1024 fp32 -> T bf16 (only launched when ws fits)
        int tid2 = bid - 2818;
        int c0 = (tid2 & 15) * 64, r0 = (tid2 >> 4) * 64;
        for (int i = 0; i < 16; i++) {
            int idx = t + i * 256;
            int lr = idx >> 6, lc = idx & 63;
            tile[lr][lc] = f2bf(wproj[(size_t)(r0 + lr) * 1024 + c0 + lc]);
        }
        __syncthreads();
        for (int i = 0; i < 16; i++) {
            int idx = t + i * 256;
            int lr = idx >> 6, lc = idx & 63;
            wprojT[(size_t)(c0 + lr) * 1024 + r0 + lc] = tile[lc][lr];
        }
    }
}

// ---------- transpose+convert: in fp32 [R][C] -> out bf16 [C][R] (fallback path) ----------
__global__ __launch_bounds__(256) void transpose_f32_bf16(const float* __restrict__ in,
                                                          ushort_t* __restrict__ out,
                                                          int R, int C) {
    __shared__ __align__(16) ushort_t tile[64][65];
    int c0 = blockIdx.x * 64, r0 = blockIdx.y * 64;
    int t = threadIdx.x;
    for (int i = 0; i < 16; i++) {
        int idx = t + i * 256;
        int lr = idx >> 6, lc = idx & 63;
        tile[lr][lc] = f2bf(in[(size_t)(r0 + lr) * C + c0 + lc]);
    }
    __syncthreads();
    for (int i = 0; i < 16; i++) {
        int idx = t + i * 256;
        int lr = idx >> 6, lc = idx & 63;
        out[(size_t)(c0 + lr) * R + r0 + lc] = tile[lc][lr];
    }
}

// ---------- GEMM1 r13: Q all rows; K/V valid rows only; BALANCED dispatch order ----------
// wid = x + 24*y. Work order: [0,256) Q tiles (uniform cost); [256,512) KV slot-tiles
// st<8 (~all live at ~50% pad, uniform cost); [512,768) KV st>=8 (~all dead, instant
// exit). Dispatch rounds are therefore uniform: round1 = Q (1 block/CU), round2 =
// live KV, round3 drains free -> worst-CU chain = 2 live blocks (was ~3 with the
// hash-scattered dead bands of r12). Consecutive wids share A/B panels for L2.
__global__ __launch_bounds__(256) void gemm_qkv(
    const ushort_t* __restrict__ A, const ushort_t* __restrict__ Bt,
    const int* __restrict__ tbl,
    ushort_t* __restrict__ outQ, ushort_t* __restrict__ outK, ushort_t* __restrict__ outV) {
    const int K = 1024;
    __shared__ __align__(16) ushort_t As[128 * 64];
    __shared__ __align__(16) ushort_t Bs[128 * 64];
    const int* idxmap = tbl + 8192;
    const int* vcp = tbl + 12288;
    int t = threadIdx.x;
    int w = t >> 6, lane = t & 63;
    int quad = lane >> 4, l15 = lane & 15;
    int wM = w >> 1, wN = w & 1;
    int lrow = lane >> 3;
    int lcol8 = (lane & 7) * 8;

    int wid = blockIdx.x + 24 * blockIdx.y;
    bool isQ = wid < 256;
    int b = 0, m0, vc = 0, tNr;
    size_t arow[4];
    if (isQ) {
        tNr = (wid & 7) * 128;               // B rows (= output cols) [0,1024)
        m0 = (wid >> 3) * 128;               // global row base [0,4096)
        for (int i = 0; i < 4; i++)
            arow[i] = (size_t)(m0 + w * 32 + i * 8 + lrow) * K;
    } else {
        int idx = wid - 256;                 // 0..511
        int grp = idx >> 8;                  // 0: st<8 (live), 1: st>=8 (mostly dead)
        int r = idx & 255;
        int xkv = r >> 4;                    // 0..15 KV N-tile
        b = (r >> 3) & 1;
        int st = (r & 7) + grp * 8;          // compact slot tile 0..15
        tNr = 1024 + xkv * 128;              // B rows [1024,3072)
        vc = vcp[b];
        m0 = st * 128;                       // compact slot base [0,2048)
        if (m0 >= vc) return;                // whole tile is tail -> no work
        for (int i = 0; i < 4; i++) {
            int slot = m0 + w * 32 + i * 8 + lrow;
            int orig = idxmap[b * 2048 + slot];   // 2048 for tail (A read garbage, in-bounds; stores guarded)
            arow[i] = (size_t)(b * 2048 + orig) * K;
        }
    }

    float4_t acc[4][4];
    for (int i = 0; i < 4; i++)
        for (int j = 0; j < 4; j++) acc[i][j] = (float4_t){0.f, 0.f, 0.f, 0.f};

    const ushort_t* Bbase = Bt + (size_t)(tNr + w * 32) * K;

    for (int k0 = 0; k0 < K; k0 += 64) {
        __syncthreads();
        for (int i = 0; i < 4; i++) {
            const ushort_t* ga = A + arow[i] + k0 + lcol8;
            __builtin_amdgcn_global_load_lds((AS1 void*)ga, (AS3 void*)&As[(w * 32 + i * 8) * 64], 16, 0, 0);
            const ushort_t* gb = Bbase + (size_t)(i * 8 + lrow) * K + k0 + lcol8;
            __builtin_amdgcn_global_load_lds((AS1 void*)gb, (AS3 void*)&Bs[(w * 32 + i * 8) * 64], 16, 0, 0);
        }
        __syncthreads();
        for (int kt = 0; kt < 2; kt++) {
            short8 af[4], bf[4];
            for (int m = 0; m < 4; m++)
                af[m] = *(const short8*)&As[(wM * 64 + m * 16 + l15) * 64 + kt * 32 + quad * 8];
            for (int n = 0; n < 4; n++)
                bf[n] = *(const short8*)&Bs[(wN * 64 + n * 16 + l15) * 64 + kt * 32 + quad * 8];
            for (int m = 0; m < 4; m++)
                for (int n = 0; n < 4; n++)
                    acc[m][n] = __builtin_amdgcn_mfma_f32_16x16x32_bf16(af[m], bf[n], acc[m][n], 0, 0, 0);
        }
    }

    for (int m = 0; m < 4; m++) {
        int lm = wM * 64 + m * 16 + quad * 4;     // local row within the 128-row tile
        for (int n = 0; n < 4; n++) {
            int lnc = wN * 64 + n * 16 + l15;     // local col within the 128-col tile
            if (isQ) {
                int gn = tNr + lnc;               // [0,1024)
                int h = gn >> 6, dd = gn & 63;
                for (int r = 0; r < 4; r++) {
                    int row = m0 + lm + r;
                    int bb = row >> 11, ns = row & 2047;
                    outQ[(((size_t)(bb * 16 + h) * 2048 + ns) << 6) + dd] = f2bf(acc[m][n][r]);
                }
            } else {
                int gnc = tNr - 1024 + lnc;       // [0,2048): K then V
                ushort_t* dst = (gnc < 1024) ? outK : outV;
                int hh = (gnc >> 6) & 15, dd = gnc & 63;
                for (int r = 0; r < 4; r++) {
                    int slot = m0 + lm + r;
                    if (slot < vc)
                        dst[(((size_t)(b * 16 + hh) * 2048 + slot) << 6) + dd] = f2bf(acc[m][n][r]);
                }
            }
        }
    }
}

// ---------- flash attention r11: r8 structure over COMPACTED keys (unchanged, verified) ----------
__global__ __launch_bounds__(512, 4) void attn_kernel(
    const ushort_t* __restrict__ q, const ushort_t* __restrict__ k,
    const ushort_t* __restrict__ v, const int* __restrict__ tbl,
    const int* __restrict__ csp, ushort_t* __restrict__ out) {
    __shared__ __align__(16) ushort_t Ks[2][64 * 64];    // [slot][dd], XOR-swizzled
    __shared__ __align__(16) ushort_t VsT[2][64 * 64];   // [dd][slot], XOR-swizzled
    __shared__ __align__(16) ushort_t Ps[8][16 * 64];    // per-wave P tile
    __shared__ int Idx[2048];                            // slot -> orig key index

    const int* pref = tbl + 4096;
    const int* idxmap = tbl + 8192;
    const int* vcp = tbl + 12288;

    int cs = csp[0];
    int t = threadIdx.x, w = t >> 6, lane = t & 63;
    int quad = lane >> 4, l15 = lane & 15;
    int bh = blockIdx.y;
    int b = bh >> 4, h = bh & 15;
    int g = (blockIdx.y < 16) ? blockIdx.x : 15 - blockIdx.x;
    int q0 = g * 128;
    int rowmin = q0 + w * 16;
    const float c1 = 0.18033688f;    // 0.125 * log2(e)
    const float c2 = -11.541560f;    // -8 * log2(e)

    // keys needed: orig < bound = max(rowmax+1, cs); count them in compact space
    int bound = q0 + 128; if (cs > bound) bound = cs;
    int nvalid = (bound > 2047) ? vcp[b] : pref[b * 2048 + bound];
    int nT = (nvalid + 63) >> 6; if (nT < 1) nT = 1;

    for (int i = 0; i < 4; i++) Idx[t + i * 512] = idxmap[b * 2048 + t + i * 512];

    const ushort_t* qb = q + ((size_t)bh * 2048 + rowmin + l15) * 64;
    short8 qf0 = *(const short8*)(qb + quad * 8);
    short8 qf1 = *(const short8*)(qb + 32 + quad * 8);

    float4_t O[4];
    for (int i = 0; i < 4; i++) O[i] = (float4_t){0.f, 0.f, 0.f, 0.f};
    float ls[4] = {0.f, 0.f, 0.f, 0.f};

    const ushort_t* kbase = k + (size_t)bh * 2048 * 64;
    const ushort_t* vbase = v + (size_t)bh * 2048 * 64;

    int lrow = lane >> 3, lblk = lane & 7;
    int prow = rowmin + quad * 4;
    int sw = l15 & 7;

    short8 vr;   // V register-prefetch (one 8-col strip per wave)
    auto stageK = [&](int it, int buf) {
        int k0 = it * 64;
        const ushort_t* gk = kbase + (size_t)(k0 + w * 8 + lrow) * 64 + ((lblk ^ lrow) * 8);
        __builtin_amdgcn_global_load_lds((AS1 void*)gk, (AS3 void*)&Ks[buf][w * 8 * 64], 16, 0, 0);
    };
    auto loadV = [&](int it) {
        vr = *(const short8*)(vbase + (size_t)(it * 64 + lane) * 64 + w * 8);
        if (it * 64 + lane >= nvalid)
            for (int j = 0; j < 8; j++) vr[j] = 0;
    };

    stageK(0, 0);
    loadV(0);

    for (int it = 0; it < nT; it++) {
        int cur = it & 1, nxt = cur ^ 1;
        for (int j = 0; j < 8; j++) {
            int sl = ((lrow ^ j) * 8) + lblk;
            VsT[cur][(w * 8 + j) * 64 + sl] = (ushort_t)vr[j];
        }
        __syncthreads();  // drains this tile's K glds; VsT[cur] + Idx visible
        if (it + 1 < nT) {
            stageK(it + 1, nxt);
            loadV(it + 1);
        }

        int k0 = it * 64;
        int omin = Idx[k0];
        // tile fully masked for this wave? (min orig > all rows and >= cs)
        bool act = (omin <= rowmin + 15) || (omin < cs);
        if (act) {
            int omax = Idx[k0 + 63];
            bool needC = (omax > rowmin) && (omax >= cs);

            short8 kf0[4], kf1[4];
            for (int ks = 0; ks < 4; ks++) {
                const ushort_t* krow = &Ks[cur][(ks * 16 + l15) * 64];
                kf0[ks] = *(const short8*)(krow + (quad ^ sw) * 8);
                kf1[ks] = *(const short8*)(krow + ((4 + quad) ^ sw) * 8);
            }

            float4_t s[4];
            for (int ks = 0; ks < 4; ks++) {
                float4_t a = (float4_t){0.f, 0.f, 0.f, 0.f};
                a = __builtin_amdgcn_mfma_f32_16x16x32_bf16(qf0, kf0[ks], a, 0, 0, 0);
                a = __builtin_amdgcn_mfma_f32_16x16x32_bf16(qf1, kf1[ks], a, 0, 0, 0);
                s[ks] = a;
            }
            for (int ks = 0; ks < 4; ks++) {
                int key = Idx[k0 + ks * 16 + l15];   // orig index; 2048 for tail
                for (int r = 0; r < 4; r++) {
                    float arg = s[ks][r] * c1 + c2;
                    if (needC && (key > prow + r) && (key >= cs)) arg = -1e38f;
                    float p = __builtin_amdgcn_exp2f(arg);
                    ls[r] += p;
                    int row = quad * 4 + r;
                    Ps[w][row * 64 + (((ks * 2 + (l15 >> 3)) ^ (row & 7)) * 8) + (l15 & 7)] = f2bf_trunc(p);
                }
            }

            short8 vf0[4], vf1[4];
            for (int n = 0; n < 4; n++) {
                const ushort_t* vrow = &VsT[cur][(n * 16 + l15) * 64];
                vf0[n] = *(const short8*)(vrow + (quad ^ sw) * 8);
                vf1[n] = *(const short8*)(vrow + ((4 + quad) ^ sw) * 8);
            }
            const ushort_t* prl = &Ps[w][l15 * 64];
            short8 pf0 = *(const short8*)(prl + (quad ^ sw) * 8);
            short8 pf1 = *(const short8*)(prl + ((4 + quad) ^ sw) * 8);
            for (int n = 0; n < 4; n++) {
                O[n] = __builtin_amdgcn_mfma_f32_16x16x32_bf16(pf0, vf0[n], O[n], 0, 0, 0);
                O[n] = __builtin_amdgcn_mfma_f32_16x16x32_bf16(pf1, vf1[n], O[n], 0, 0, 0);
            }
        }
    }

    for (int r = 0; r < 4; r++) {
        float l = ls[r];
        l += __shfl_xor(l, 1, 64); l += __shfl_xor(l, 2, 64);
        l += __shfl_xor(l, 4, 64); l += __shfl_xor(l, 8, 64);
        float inv = l > 0.f ? 1.f / l : 0.f;
        int row = rowmin + quad * 4 + r;
        size_t ob = ((size_t)b * 2048 + row) * 1024 + h * 64;
        for (int n = 0; n < 4; n++)
            out[ob + n * 16 + l15] = f2bf(O[n][r] * inv);
    }
}

// ---------- GEMM2: out = ao @ wprojT^T + bias (bf16 A via glds, fp32 out) ----------
__global__ __launch_bounds__(256) void gemm_out_k(
    const ushort_t* __restrict__ A, const ushort_t* __restrict__ Bt,
    const float* __restrict__ bias, float* __restrict__ outC) {
    const int K = 1024, N = 1024;
    __shared__ __align__(16) ushort_t As[128 * 64];
    __shared__ __align__(16) ushort_t Bs[128 * 64];
    int t = threadIdx.x;
    int w = t >> 6, lane = t & 63;
    int quad = lane >> 4, l15 = lane & 15;
    int wM = w >> 1, wN = w & 1;
    int tM = blockIdx.y * 128, tN = blockIdx.x * 128;

    float4_t acc[4][4];
    for (int i = 0; i < 4; i++)
        for (int j = 0; j < 4; j++) acc[i][j] = (float4_t){0.f, 0.f, 0.f, 0.f};

    int lrow = lane >> 3;
    int lcol8 = (lane & 7) * 8;

    const ushort_t* Abase = A + (size_t)(tM + w * 32) * K;
    const ushort_t* Bbase = Bt + (size_t)(tN + w * 32) * K;

    for (int k0 = 0; k0 < K; k0 += 64) {
        __syncthreads();
        for (int i = 0; i < 4; i++) {
            const ushort_t* ga = Abase + (size_t)(i * 8 + lrow) * K + k0 + lcol8;
            __builtin_amdgcn_global_load_lds((AS1 void*)ga, (AS3 void*)&As[(w * 32 + i * 8) * 64], 16, 0, 0);
            const ushort_t* gb = Bbase + (size_t)(i * 8 + lrow) * K + k0 + lcol8;
            __builtin_amdgcn_global_load_lds((AS1 void*)gb, (AS3 void*)&Bs[(w * 32 + i * 8) * 64], 16, 0, 0);
        }
        __syncthreads();
        for (int kt = 0; kt < 2; kt++) {
            short8 af[4], bf[4];
            for (int m = 0; m < 4; m++)
                af[m] = *(const short8*)&As[(wM * 64 + m * 16 + l15) * 64 + kt * 32 + quad * 8];
            for (int n = 0; n < 4; n++)
                bf[n] = *(const short8*)&Bs[(wN * 64 + n * 16 + l15) * 64 + kt * 32 + quad * 8];
            for (int m = 0; m < 4; m++)
                for (int n = 0; n < 4; n++)
                    acc[m][n] = __builtin_amdgcn_mfma_f32_16x16x32_bf16(af[m], bf[n], acc[m][n], 0, 0, 0);
        }
    }

    for (int m = 0; m < 4; m++) {
        int gm = tM + wM * 64 + m * 16 + quad * 4;
        for (int n = 0; n < 4; n++) {
            int gn = tN + wN * 64 + n * 16 + l15;
            float bv = bias[gn];
            for (int r = 0; r < 4; r++)
                outC[(size_t)(gm + r) * N + gn] = acc[m][n][r] + bv;
        }
    }
}

extern "C" void kernel_launch(void* const* d_in, const int* in_sizes, int n_in,
                              void* d_out, int out_size, void* d_ws, size_t ws_size,
                              hipStream_t stream) {
    const float* x = (const float*)d_in[0];
    const int* pad = (const int*)d_in[1];
    const int* cs = (const int*)d_in[2];
    const float* wqkv = (const float*)d_in[3];
    const float* wproj = (const float*)d_in[4];
    const float* bproj = (const float*)d_in[5];
    float* out = (float*)d_out;

    // ws (base plan 32 MB, lifetimes audited):
    //   q[0,8M) k[8,16M) v[16,24M)        gemm1 -> attn (k/v compacted; tail rows garbage,
    //                                     handled by Idx mask + loadV zeroing)
    //   wqkvT[24,30M)                     prep -> gemm1 (dies)
    //   ao bf16 [24,32M)                  attn -> gemm2 (over dead wqkvT)
    //   wprojT: if ws >= 34MB -> ws[32M,34M) (written by prep, untouched after);
    //           else -> ws[0,2M) over dead q, via separate transpose after attn.
    // d_out (16MB): xbf bf16 [0,8M) prep -> gemm1 (dies);
    //   scan tables int32 @8M: cvtab[2][2048], pref[2][2048], idxmap[2][2048], vcp[2]
    //   (prep scan -> gemm1 (idxmap/vcp) + attn (pref/idxmap/vcp); dead before gemm2
    //   overwrites d_out with the final fp32 output).
    ushort_t* ws = (ushort_t*)d_ws;
    ushort_t* qws = ws;
    ushort_t* kws = ws + (size_t)4194304;
    ushort_t* vws = ws + (size_t)8388608;
    ushort_t* wqkvT = ws + (size_t)12582912;
    ushort_t* aows = ws + (size_t)12582912;
    ushort_t* xbf = (ushort_t*)d_out;
    int* tbl = (int*)((char*)d_out + 8388608);

    bool fused_wp = ws_size >= (size_t)34 * 1024 * 1024;
    ushort_t* wprojT = fused_wp ? ws + (size_t)16777216 : ws;

    prep_fused<<<fused_wp ? 3074 : 2818, 256, 0, stream>>>(wqkv, x, pad, wproj,
                                                           wqkvT, xbf, tbl, wprojT);
    gemm_qkv<<<dim3(24, 32), 256, 0, stream>>>(xbf, wqkvT, tbl, qws, kws, vws);
    attn_kernel<<<dim3(16, 32), 512, 0, stream>>>(qws, kws, vws, tbl, cs, aows);
    if (!fused_wp)
        transpose_f32_bf16<<<dim3(16, 16), 256, 0, stream>>>(wproj, wprojT, 1024, 1024);
    gemm_out_k<<<dim3(8, 32), 256, 0, stream>>>(aows, wprojT, bproj, out);
}

// Round 10
// 174.496 us; speedup vs baseline: 1.4803x; 1.0048x over previous
//
#include <hip/hip_runtime.h>
#include <stdint.h>

typedef unsigned short ushort_t;
typedef __attribute__((ext_vector_type(4))) unsigned short ushort4_t;
typedef __attribute__((ext_vector_type(8))) short short8;
typedef __attribute__((ext_vector_type(4))) float float4_t;

#define AS1 __attribute__((address_space(1)))
#define AS3 __attribute__((address_space(3)))

__device__ inline ushort_t f2bf(float f) {
    unsigned x = __builtin_bit_cast(unsigned, f);
    unsigned r = x + 0x7fffu + ((x >> 16) & 1u);
    return (ushort_t)(r >> 16);
}
__device__ inline ushort_t f2bf_trunc(float f) {
    return (ushort_t)(__builtin_bit_cast(unsigned, f) >> 16);
}

// ---------- fused prep: transpose W_qkv + convert x + pad scan (+ optional wproj^T) ----------
__global__ __launch_bounds__(256) void prep_fused(
    const float* __restrict__ wqkv, const float* __restrict__ x,
    const int* __restrict__ pad, const float* __restrict__ wproj,
    ushort_t* __restrict__ wqkvT, ushort_t* __restrict__ xbf,
    int* __restrict__ tbl, ushort_t* __restrict__ wprojT) {
    __shared__ __align__(16) ushort_t tile[64][65];
    __shared__ int wsum[4];
    int bid = blockIdx.x, t = threadIdx.x;
    if (bid < 768) {
        int bx = bid % 48, by = bid / 48;
        int c0 = bx * 64, r0 = by * 64;
        for (int i = 0; i < 16; i++) {
            int idx = t + i * 256;
            int lr = idx >> 6, lc = idx & 63;
            tile[lr][lc] = f2bf(wqkv[(size_t)(r0 + lr) * 3072 + c0 + lc]);
        }
        __syncthreads();
        for (int i = 0; i < 16; i++) {
            int idx = t + i * 256;
            int lr = idx >> 6, lc = idx & 63;
            wqkvT[(size_t)(c0 + lr) * 1024 + r0 + lc] = tile[lc][lr];
        }
    } else if (bid < 2816) {
        size_t i = ((size_t)(bid - 768) * 256 + t) * 8;
        float4_t a = *(const float4_t*)(x + i);
        float4_t b = *(const float4_t*)(x + i + 4);
        ushort_t u[8];
        u[0] = f2bf(a.x); u[1] = f2bf(a.y); u[2] = f2bf(a.z); u[3] = f2bf(a.w);
        u[4] = f2bf(b.x); u[5] = f2bf(b.y); u[6] = f2bf(b.z); u[7] = f2bf(b.w);
        *(ushort4_t*)(xbf + i) = *(ushort4_t*)&u[0];
        *(ushort4_t*)(xbf + i + 4) = *(ushort4_t*)&u[4];
    } else if (bid < 2818) {
        // per-batch prefix scan of padding mask (valid = pad==0)
        int b = bid - 2816;
        int* cvtab = tbl;
        int* pref = tbl + 4096;
        int* idxmap = tbl + 8192;
        int* vcp = tbl + 12288;
        int lane = t & 63, w4 = t >> 6;
        int base0 = t * 8;
        int v[8], s8 = 0;
        for (int j = 0; j < 8; j++) {
            v[j] = (pad[b * 2048 + base0 + j] == 0) ? 1 : 0;
            s8 += v[j];
        }
        int incl = s8;
        for (int off = 1; off < 64; off <<= 1) {
            int y = __shfl_up(incl, off, 64);
            if (lane >= off) incl += y;
        }
        int excl = incl - s8;
        if (lane == 63) wsum[w4] = incl;
        __syncthreads();
        int wbase = 0;
        for (int ww = 0; ww < 4; ww++) if (ww < w4) wbase += wsum[ww];
        int vcall = wsum[0] + wsum[1] + wsum[2] + wsum[3];
        int run = wbase + excl;
        for (int j = 0; j < 8; j++) {
            int pos = base0 + j;
            pref[b * 2048 + pos] = run;
            cvtab[b * 2048 + pos] = v[j] ? run : -1;
            if (v[j]) idxmap[b * 2048 + run] = pos;
            run += v[j];
        }
        if (t == 0) vcp[b] = vcall;
        for (int s = vcall + t; s < 2048; s += 256) idxmap[b * 2048 + s] = 2048;
    } else {
        // fused wproj transpose: 1024x1024 fp32 -> T bf16 (only launched when ws fits)
        int tid2 = bid - 2818;
        int c0 = (tid2 & 15) * 64, r0 = (tid2 >> 4) * 64;
        for (int i = 0; i < 16; i++) {
            int idx = t + i * 256;
            int lr = idx >> 6, lc = idx & 63;
            tile[lr][lc] = f2bf(wproj[(size_t)(r0 + lr) * 1024 + c0 + lc]);
        }
        __syncthreads();
        for (int i = 0; i < 16; i++) {
            int idx = t + i * 256;
            int lr = idx >> 6, lc = idx & 63;
            wprojT[(size_t)(c0 + lr) * 1024 + r0 + lc] = tile[lc][lr];
        }
    }
}

// ---------- transpose+convert (fallback path) ----------
__global__ __launch_bounds__(256) void transpose_f32_bf16(const float* __restrict__ in,
                                                          ushort_t* __restrict__ out,
                                                          int R, int C) {
    __shared__ __align__(16) ushort_t tile[64][65];
    int c0 = blockIdx.x * 64, r0 = blockIdx.y * 64;
    int t = threadIdx.x;
    for (int i = 0; i < 16; i++) {
        int idx = t + i * 256;
        int lr = idx >> 6, lc = idx & 63;
        tile[lr][lc] = f2bf(in[(size_t)(r0 + lr) * C + c0 + lc]);
    }
    __syncthreads();
    for (int i = 0; i < 16; i++) {
        int idx = t + i * 256;
        int lr = idx >> 6, lc = idx & 63;
        out[(size_t)(c0 + lr) * R + r0 + lc] = tile[lc][lr];
    }
}

// ---------- GEMM1 r14: split-K 8-wave blocks; Q all rows, K/V valid rows; balanced order ----------
// 512 thr: waves 0-3 (kh=0) K[0,512), waves 4-7 (kh=1) K[512,1024). Each half has its
// own As/Bs (smem[kh], smem[2+kh]) -> 64KB LDS, 2 blocks/CU co-resident = 16 waves/CU
// (was 1 block x 4 waves at R8's Occupancy 10.8%). Per-block barrier chain 16 -> 8
// K-steps. After the loop, kh=1 waves dump acc into the dead staging LDS (fp32,
// lane-contiguous -> conflict-free), kh=0 waves add + run the unchanged epilogue.
// Work order (wid = x + 24*y): [0,256) Q tiles; [256,512) KV slot-tiles st<8 (live);
// [512,768) KV st>=8 (dead, instant exit) -> uniform dispatch rounds.
__global__ __launch_bounds__(512, 4) void gemm_qkv(
    const ushort_t* __restrict__ A, const ushort_t* __restrict__ Bt,
    const int* __restrict__ tbl,
    ushort_t* __restrict__ outQ, ushort_t* __restrict__ outK, ushort_t* __restrict__ outV) {
    const int K = 1024;
    __shared__ __align__(16) ushort_t smem[4][128 * 64];   // [kh]=As, [2+kh]=Bs; reused as fp32 redbuf
    const int* idxmap = tbl + 8192;
    const int* vcp = tbl + 12288;
    int t = threadIdx.x;
    int w = t >> 6, lane = t & 63;
    int wq = w & 3, kh = w >> 2;
    int quad = lane >> 4, l15 = lane & 15;
    int wM = wq >> 1, wN = wq & 1;
    int lrow = lane >> 3;
    int lcol8 = (lane & 7) * 8;

    int wid = blockIdx.x + 24 * blockIdx.y;
    bool isQ = wid < 256;
    int b = 0, m0, vc = 0, tNr;
    size_t arow[4];
    if (isQ) {
        tNr = (wid & 7) * 128;               // output cols [0,1024)
        m0 = (wid >> 3) * 128;               // global row base [0,4096)
        for (int i = 0; i < 4; i++)
            arow[i] = (size_t)(m0 + wq * 32 + i * 8 + lrow) * K;
    } else {
        int idx = wid - 256;                 // 0..511
        int grp = idx >> 8;                  // 0: st<8 (live), 1: st>=8 (mostly dead)
        int r = idx & 255;
        int xkv = r >> 4;                    // KV N-tile 0..15
        b = (r >> 3) & 1;
        int st = (r & 7) + grp * 8;          // compact slot tile 0..15
        tNr = 1024 + xkv * 128;              // B rows [1024,3072)
        vc = vcp[b];
        m0 = st * 128;                       // compact slot base
        if (m0 >= vc) return;                // whole tile is tail -> no work (uniform)
        for (int i = 0; i < 4; i++) {
            int slot = m0 + wq * 32 + i * 8 + lrow;
            int orig = idxmap[b * 2048 + slot];   // 2048 for tail (in-bounds garbage; stores guarded)
            arow[i] = (size_t)(b * 2048 + orig) * K;
        }
    }

    float4_t acc[4][4];
    for (int i = 0; i < 4; i++)
        for (int j = 0; j < 4; j++) acc[i][j] = (float4_t){0.f, 0.f, 0.f, 0.f};

    const ushort_t* Bbase = Bt + (size_t)(tNr + wq * 32) * K;
    const int kb = kh * 512;

    for (int k0 = 0; k0 < 512; k0 += 64) {
        __syncthreads();
        for (int i = 0; i < 4; i++) {
            const ushort_t* ga = A + arow[i] + kb + k0 + lcol8;
            __builtin_amdgcn_global_load_lds((AS1 void*)ga, (AS3 void*)&smem[kh][(wq * 32 + i * 8) * 64], 16, 0, 0);
            const ushort_t* gb = Bbase + (size_t)(i * 8 + lrow) * K + kb + k0 + lcol8;
            __builtin_amdgcn_global_load_lds((AS1 void*)gb, (AS3 void*)&smem[2 + kh][(wq * 32 + i * 8) * 64], 16, 0, 0);
        }
        __syncthreads();
        for (int kt = 0; kt < 2; kt++) {
            short8 af[4], bf[4];
            for (int m = 0; m < 4; m++)
                af[m] = *(const short8*)&smem[kh][(wM * 64 + m * 16 + l15) * 64 + kt * 32 + quad * 8];
            for (int n = 0; n < 4; n++)
                bf[n] = *(const short8*)&smem[2 + kh][(wN * 64 + n * 16 + l15) * 64 + kt * 32 + quad * 8];
            for (int m = 0; m < 4; m++)
                for (int n = 0; n < 4; n++)
                    acc[m][n] = __builtin_amdgcn_mfma_f32_16x16x32_bf16(af[m], bf[n], acc[m][n], 0, 0, 0);
        }
    }

    // cross-half reduction: kh=1 -> LDS (fp32, lane-contiguous), kh=0 adds
    __syncthreads();
    float4_t* red = (float4_t*)smem;   // 4096 float4s = 64KB
    if (kh == 1) {
        for (int m = 0; m < 4; m++)
            for (int n = 0; n < 4; n++)
                red[(wq * 16 + m * 4 + n) * 64 + lane] = acc[m][n];
    }
    __syncthreads();
    if (kh == 1) return;
    for (int m = 0; m < 4; m++)
        for (int n = 0; n < 4; n++) {
            float4_t o = red[(wq * 16 + m * 4 + n) * 64 + lane];
            acc[m][n].x += o.x; acc[m][n].y += o.y;
            acc[m][n].z += o.z; acc[m][n].w += o.w;
        }

    for (int m = 0; m < 4; m++) {
        int lm = wM * 64 + m * 16 + quad * 4;     // local row within the 128-row tile
        for (int n = 0; n < 4; n++) {
            int lnc = wN * 64 + n * 16 + l15;     // local col within the 128-col tile
            if (isQ) {
                int gn = tNr + lnc;               // [0,1024)
                int h = gn >> 6, dd = gn & 63;
                for (int r = 0; r < 4; r++) {
                    int row = m0 + lm + r;
                    int bb = row >> 11, ns = row & 2047;
                    outQ[(((size_t)(bb * 16 + h) * 2048 + ns) << 6) + dd] = f2bf(acc[m][n][r]);
                }
            } else {
                int gnc = tNr - 1024 + lnc;       // [0,2048): K then V
                ushort_t* dst = (gnc < 1024) ? outK : outV;
                int hh = (gnc >> 6) & 15, dd = gnc & 63;
                for (int r = 0; r < 4; r++) {
                    int slot = m0 + lm + r;
                    if (slot < vc)
                        dst[(((size_t)(b * 16 + hh) * 2048 + slot) << 6) + dd] = f2bf(acc[m][n][r]);
                }
            }
        }
    }
}

// ---------- flash attention r11: r8 structure over COMPACTED keys (unchanged, verified) ----------
__global__ __launch_bounds__(512, 4) void attn_kernel(
    const ushort_t* __restrict__ q, const ushort_t* __restrict__ k,
    const ushort_t* __restrict__ v, const int* __restrict__ tbl,
    const int* __restrict__ csp, ushort_t* __restrict__ out) {
    __shared__ __align__(16) ushort_t Ks[2][64 * 64];    // [slot][dd], XOR-swizzled
    __shared__ __align__(16) ushort_t VsT[2][64 * 64];   // [dd][slot], XOR-swizzled
    __shared__ __align__(16) ushort_t Ps[8][16 * 64];    // per-wave P tile
    __shared__ int Idx[2048];                            // slot -> orig key index

    const int* pref = tbl + 4096;
    const int* idxmap = tbl + 8192;
    const int* vcp = tbl + 12288;

    int cs = csp[0];
    int t = threadIdx.x, w = t >> 6, lane = t & 63;
    int quad = lane >> 4, l15 = lane & 15;
    int bh = blockIdx.y;
    int b = bh >> 4, h = bh & 15;
    int g = (blockIdx.y < 16) ? blockIdx.x : 15 - blockIdx.x;
    int q0 = g * 128;
    int rowmin = q0 + w * 16;
    const float c1 = 0.18033688f;    // 0.125 * log2(e)
    const float c2 = -11.541560f;    // -8 * log2(e)

    int bound = q0 + 128; if (cs > bound) bound = cs;
    int nvalid = (bound > 2047) ? vcp[b] : pref[b * 2048 + bound];
    int nT = (nvalid + 63) >> 6; if (nT < 1) nT = 1;

    for (int i = 0; i < 4; i++) Idx[t + i * 512] = idxmap[b * 2048 + t + i * 512];

    const ushort_t* qb = q + ((size_t)bh * 2048 + rowmin + l15) * 64;
    short8 qf0 = *(const short8*)(qb + quad * 8);
    short8 qf1 = *(const short8*)(qb + 32 + quad * 8);

    float4_t O[4];
    for (int i = 0; i < 4; i++) O[i] = (float4_t){0.f, 0.f, 0.f, 0.f};
    float ls[4] = {0.f, 0.f, 0.f, 0.f};

    const ushort_t* kbase = k + (size_t)bh * 2048 * 64;
    const ushort_t* vbase = v + (size_t)bh * 2048 * 64;

    int lrow = lane >> 3, lblk = lane & 7;
    int prow = rowmin + quad * 4;
    int sw = l15 & 7;

    short8 vr;   // V register-prefetch (one 8-col strip per wave)
    auto stageK = [&](int it, int buf) {
        int k0 = it * 64;
        const ushort_t* gk = kbase + (size_t)(k0 + w * 8 + lrow) * 64 + ((lblk ^ lrow) * 8);
        __builtin_amdgcn_global_load_lds((AS1 void*)gk, (AS3 void*)&Ks[buf][w * 8 * 64], 16, 0, 0);
    };
    auto loadV = [&](int it) {
        vr = *(const short8*)(vbase + (size_t)(it * 64 + lane) * 64 + w * 8);
        if (it * 64 + lane >= nvalid)
            for (int j = 0; j < 8; j++) vr[j] = 0;
    };

    stageK(0, 0);
    loadV(0);

    for (int it = 0; it < nT; it++) {
        int cur = it & 1, nxt = cur ^ 1;
        for (int j = 0; j < 8; j++) {
            int sl = ((lrow ^ j) * 8) + lblk;
            VsT[cur][(w * 8 + j) * 64 + sl] = (ushort_t)vr[j];
        }
        __syncthreads();  // drains this tile's K glds; VsT[cur] + Idx visible
        if (it + 1 < nT) {
            stageK(it + 1, nxt);
            loadV(it + 1);
        }

        int k0 = it * 64;
        int omin = Idx[k0];
        bool act = (omin <= rowmin + 15) || (omin < cs);
        if (act) {
            int omax = Idx[k0 + 63];
            bool needC = (omax > rowmin) && (omax >= cs);

            short8 kf0[4], kf1[4];
            for (int ks = 0; ks < 4; ks++) {
                const ushort_t* krow = &Ks[cur][(ks * 16 + l15) * 64];
                kf0[ks] = *(const short8*)(krow + (quad ^ sw) * 8);
                kf1[ks] = *(const short8*)(krow + ((4 + quad) ^ sw) * 8);
            }

            float4_t s[4];
            for (int ks = 0; ks < 4; ks++) {
                float4_t a = (float4_t){0.f, 0.f, 0.f, 0.f};
                a = __builtin_amdgcn_mfma_f32_16x16x32_bf16(qf0, kf0[ks], a, 0, 0, 0);
                a = __builtin_amdgcn_mfma_f32_16x16x32_bf16(qf1, kf1[ks], a, 0, 0, 0);
                s[ks] = a;
            }
            for (int ks = 0; ks < 4; ks++) {
                int key = Idx[k0 + ks * 16 + l15];   // orig index; 2048 for tail
                for (int r = 0; r < 4; r++) {
                    float arg = s[ks][r] * c1 + c2;
                    if (needC && (key > prow + r) && (key >= cs)) arg = -1e38f;
                    float p = __builtin_amdgcn_exp2f(arg);
                    ls[r] += p;
                    int row = quad * 4 + r;
                    Ps[w][row * 64 + (((ks * 2 + (l15 >> 3)) ^ (row & 7)) * 8) + (l15 & 7)] = f2bf_trunc(p);
                }
            }

            short8 vf0[4], vf1[4];
            for (int n = 0; n < 4; n++) {
                const ushort_t* vrow = &VsT[cur][(n * 16 + l15) * 64];
                vf0[n] = *(const short8*)(vrow + (quad ^ sw) * 8);
                vf1[n] = *(const short8*)(vrow + ((4 + quad) ^ sw) * 8);
            }
            const ushort_t* prl = &Ps[w][l15 * 64];
            short8 pf0 = *(const short8*)(prl + (quad ^ sw) * 8);
            short8 pf1 = *(const short8*)(prl + ((4 + quad) ^ sw) * 8);
            for (int n = 0; n < 4; n++) {
                O[n] = __builtin_amdgcn_mfma_f32_16x16x32_bf16(pf0, vf0[n], O[n], 0, 0, 0);
                O[n] = __builtin_amdgcn_mfma_f32_16x16x32_bf16(pf1, vf1[n], O[n], 0, 0, 0);
            }
        }
    }

    for (int r = 0; r < 4; r++) {
        float l = ls[r];
        l += __shfl_xor(l, 1, 64); l += __shfl_xor(l, 2, 64);
        l += __shfl_xor(l, 4, 64); l += __shfl_xor(l, 8, 64);
        float inv = l > 0.f ? 1.f / l : 0.f;
        int row = rowmin + quad * 4 + r;
        size_t ob = ((size_t)b * 2048 + row) * 1024 + h * 64;
        for (int n = 0; n < 4; n++)
            out[ob + n * 16 + l15] = f2bf(O[n][r] * inv);
    }
}

// ---------- GEMM2 r14: split-K 8-wave, out = ao @ wprojT^T + bias ----------
__global__ __launch_bounds__(512, 4) void gemm_out_k(
    const ushort_t* __restrict__ A, const ushort_t* __restrict__ Bt,
    const float* __restrict__ bias, float* __restrict__ outC) {
    const int K = 1024, N = 1024;
    __shared__ __align__(16) ushort_t smem[4][128 * 64];
    int t = threadIdx.x;
    int w = t >> 6, lane = t & 63;
    int wq = w & 3, kh = w >> 2;
    int quad = lane >> 4, l15 = lane & 15;
    int wM = wq >> 1, wN = wq & 1;
    int tM = blockIdx.y * 128, tN = blockIdx.x * 128;

    float4_t acc[4][4];
    for (int i = 0; i < 4; i++)
        for (int j = 0; j < 4; j++) acc[i][j] = (float4_t){0.f, 0.f, 0.f, 0.f};

    int lrow = lane >> 3;
    int lcol8 = (lane & 7) * 8;

    const ushort_t* Abase = A + (size_t)(tM + wq * 32) * K;
    const ushort_t* Bbase = Bt + (size_t)(tN + wq * 32) * K;
    const int kb = kh * 512;

    for (int k0 = 0; k0 < 512; k0 += 64) {
        __syncthreads();
        for (int i = 0; i < 4; i++) {
            const ushort_t* ga = Abase + (size_t)(i * 8 + lrow) * K + kb + k0 + lcol8;
            __builtin_amdgcn_global_load_lds((AS1 void*)ga, (AS3 void*)&smem[kh][(wq * 32 + i * 8) * 64], 16, 0, 0);
            const ushort_t* gb = Bbase + (size_t)(i * 8 + lrow) * K + kb + k0 + lcol8;
            __builtin_amdgcn_global_load_lds((AS1 void*)gb, (AS3 void*)&smem[2 + kh][(wq * 32 + i * 8) * 64], 16, 0, 0);
        }
        __syncthreads();
        for (int kt = 0; kt < 2; kt++) {
            short8 af[4], bf[4];
            for (int m = 0; m < 4; m++)
                af[m] = *(const short8*)&smem[kh][(wM * 64 + m * 16 + l15) * 64 + kt * 32 + quad * 8];
            for (int n = 0; n < 4; n++)
                bf[n] = *(const short8*)&smem[2 + kh][(wN * 64 + n * 16 + l15) * 64 + kt * 32 + quad * 8];
            for (int m = 0; m < 4; m++)
                for (int n = 0; n < 4; n++)
                    acc[m][n] = __builtin_amdgcn_mfma_f32_16x16x32_bf16(af[m], bf[n], acc[m][n], 0, 0, 0);
        }
    }

    __syncthreads();
    float4_t* red = (float4_t*)smem;
    if (kh == 1) {
        for (int m = 0; m < 4; m++)
            for (int n = 0; n < 4; n++)
                red[(wq * 16 + m * 4 + n) * 64 + lane] = acc[m][n];
    }
    __syncthreads();
    if (kh == 1) return;
    for (int m = 0; m < 4; m++)
        for (int n = 0; n < 4; n++) {
            float4_t o = red[(wq * 16 + m * 4 + n) * 64 + lane];
            acc[m][n].x += o.x; acc[m][n].y += o.y;
            acc[m][n].z += o.z; acc[m][n].w += o.w;
        }

    for (int m = 0; m < 4; m++) {
        int gm = tM + wM * 64 + m * 16 + quad * 4;
        for (int n = 0; n < 4; n++) {
            int gn = tN + wN * 64 + n * 16 + l15;
            float bv = bias[gn];
            for (int r = 0; r < 4; r++)
                outC[(size_t)(gm + r) * N + gn] = acc[m][n][r] + bv;
        }
    }
}

extern "C" void kernel_launch(void* const* d_in, const int* in_sizes, int n_in,
                              void* d_out, int out_size, void* d_ws, size_t ws_size,
                              hipStream_t stream) {
    const float* x = (const float*)d_in[0];
    const int* pad = (const int*)d_in[1];
    const int* cs = (const int*)d_in[2];
    const float* wqkv = (const float*)d_in[3];
    const float* wproj = (const float*)d_in[4];
    const float* bproj = (const float*)d_in[5];
    float* out = (float*)d_out;

    // ws (base plan 32 MB, lifetimes audited):
    //   q[0,8M) k[8,16M) v[16,24M)        gemm1 -> attn (k/v compacted; tail garbage
    //                                     handled by Idx mask + loadV zeroing)
    //   wqkvT[24,30M)                     prep -> gemm1 (dies)
    //   ao bf16 [24,32M)                  attn -> gemm2 (over dead wqkvT)
    //   wprojT: if ws >= 34MB -> ws[32M,34M) (written by prep, untouched after);
    //           else -> ws[0,2M) over dead q, via separate transpose after attn.
    // d_out (16MB): xbf bf16 [0,8M) prep -> gemm1 (dies);
    //   scan tables int32 @8M (prep -> gemm1/attn; dead before gemm2 writes d_out).
    ushort_t* ws = (ushort_t*)d_ws;
    ushort_t* qws = ws;
    ushort_t* kws = ws + (size_t)4194304;
    ushort_t* vws = ws + (size_t)8388608;
    ushort_t* wqkvT = ws + (size_t)12582912;
    ushort_t* aows = ws + (size_t)12582912;
    ushort_t* xbf = (ushort_t*)d_out;
    int* tbl = (int*)((char*)d_out + 8388608);

    bool fused_wp = ws_size >= (size_t)34 * 1024 * 1024;
    ushort_t* wprojT = fused_wp ? ws + (size_t)16777216 : ws;

    prep_fused<<<fused_wp ? 3074 : 2818, 256, 0, stream>>>(wqkv, x, pad, wproj,
                                                           wqkvT, xbf, tbl, wprojT);
    gemm_qkv<<<dim3(24, 32), 512, 0, stream>>>(xbf, wqkvT, tbl, qws, kws, vws);
    attn_kernel<<<dim3(16, 32), 512, 0, stream>>>(qws, kws, vws, tbl, cs, aows);
    if (!fused_wp)
        transpose_f32_bf16<<<dim3(16, 16), 256, 0, stream>>>(wproj, wprojT, 1024, 1024);
    gemm_out_k<<<dim3(8, 32), 512, 0, stream>>>(aows, wprojT, bproj, out);
}